// Round 6
// baseline (488.130 us; speedup 1.0000x reference)
//
#include <hip/hip_runtime.h>
#include <hip/hip_bf16.h>

typedef __hip_bfloat16 bf16;
typedef short short8 __attribute__((ext_vector_type(8)));
typedef float f32x4 __attribute__((ext_vector_type(4)));
typedef float f32x2 __attribute__((ext_vector_type(2)));

#define NPB 256          // nodes per bucket (coarse radix = dst>>8)
#define MAXBUK 1024      // supports N <= 262144

__device__ __forceinline__ float bf2f_raw(unsigned short u) {
    unsigned x = ((unsigned)u) << 16; float f; __builtin_memcpy(&f, &x, 4); return f;
}
__device__ __forceinline__ unsigned short f2bf_raw(float f) {   // RNE
    unsigned u; __builtin_memcpy(&u, &f, 4);
    u += 0x7FFFu + ((u >> 16) & 1u);
    return (unsigned short)(u >> 16);
}
__device__ __forceinline__ float lo_f(unsigned u) {
    unsigned x = u << 16; float f; __builtin_memcpy(&f, &x, 4); return f;
}
__device__ __forceinline__ float hi_f(unsigned u) {
    unsigned x = u & 0xffff0000u; float f; __builtin_memcpy(&f, &x, 4); return f;
}

// ---------------- dtype sniffer: flag=1 if float arrays are f32, 0 if bf16 ----------------

__global__ __launch_bounds__(1024) void sniff_kernel(const unsigned short* __restrict__ w,
                                                     int nshorts, int* __restrict__ flag) {
    __shared__ int red[1024];
    const int t = threadIdx.x;
    int c = 0;
    for (int i = t; i < nshorts; i += 1024) {
        unsigned e = (w[i] >> 7) & 0xFFu;
        if (e >= 140u || (e >= 1u && e <= 40u)) c++;
    }
    red[t] = c;
    __syncthreads();
    for (int o = 512; o > 0; o >>= 1) {
        if (t < o) red[t] += red[t + o];
        __syncthreads();
    }
    if (t == 0) *flag = (red[0] > nshorts / 8) ? 1 : 0;
}

// ---------------- prep: biases->f32; W1/W2 -> MFMA B-fragment-linear bf16 ----------------

__global__ __launch_bounds__(256) void prep_kernel(const void* __restrict__ W1p,
                                                   const void* __restrict__ W2p,
                                                   const void* __restrict__ b1p,
                                                   const void* __restrict__ b2p,
                                                   unsigned short* __restrict__ WB1,
                                                   unsigned short* __restrict__ WB2,
                                                   float* __restrict__ b1f,
                                                   float* __restrict__ b2f,
                                                   const int* __restrict__ flag) {
    const int isf32 = *flag;
    const int t = blockIdx.x * 256 + threadIdx.x;
    const int T1 = 16384, T2 = 8192;
    if (t < T1) {
        int j = t & 7, l = (t >> 3) & 63, f = t >> 9;
        int n = f >> 2, kk = f & 3;
        int k = kk * 32 + (l >> 4) * 8 + j;
        int col = n * 16 + (l & 15);
        WB1[t] = isf32 ? f2bf_raw(((const float*)W1p)[k * 128 + col])
                       : ((const unsigned short*)W1p)[k * 128 + col];
    } else if (t < T1 + T2) {
        int o = t - T1;
        int j = o & 7, l = (o >> 3) & 63, f = o >> 9;
        int n = f >> 2, kk = f & 3;
        int k = kk * 32 + (l >> 4) * 8 + j;
        int col = n * 16 + (l & 15);
        WB2[o] = isf32 ? f2bf_raw(((const float*)W2p)[k * 64 + col])
                       : ((const unsigned short*)W2p)[k * 64 + col];
    } else if (t < T1 + T2 + 128) {
        int o = t - T1 - T2;
        b1f[o] = isf32 ? ((const float*)b1p)[o] : bf2f_raw(((const unsigned short*)b1p)[o]);
    } else if (t < T1 + T2 + 192) {
        int o = t - T1 - T2 - 128;
        b2f[o] = isf32 ? ((const float*)b2p)[o] : bf2f_raw(((const unsigned short*)b2p)[o]);
    }
}

// ---------------- CSR build, bucket-granular ----------------

__global__ __launch_bounds__(256) void ms_count_kernel(const int* __restrict__ dst,
                                                       int* __restrict__ bktcnt,
                                                       int E, int nbuk) {
    __shared__ int cnt[MAXBUK];
    const int t = threadIdx.x;
    const int e0 = blockIdx.x * 4096;
    const int e1 = min(E, e0 + 4096);
    for (int b = t; b < nbuk; b += 256) cnt[b] = 0;
    __syncthreads();
    for (int e = e0 + t; e < e1; e += 256) atomicAdd(&cnt[dst[e] >> 8], 1);
    __syncthreads();
    for (int b = t; b < nbuk; b += 256) {
        int c = cnt[b];
        if (c) atomicAdd(&bktcnt[b], c);
    }
}

__global__ __launch_bounds__(1024) void bscan_kernel(const int* __restrict__ bktcnt,
                                                     int* __restrict__ bofs,
                                                     int* __restrict__ bcur,
                                                     int nbuk, int total) {
    __shared__ int ps[1024];
    const int t = threadIdx.x;
    int v = (t < nbuk) ? bktcnt[t] : 0;
    ps[t] = v;
    __syncthreads();
    for (int o = 1; o < 1024; o <<= 1) {
        int u = (t >= o) ? ps[t - o] : 0;
        __syncthreads();
        ps[t] += u;
        __syncthreads();
    }
    if (t < nbuk) {
        int ex = ps[t] - v;
        bofs[t] = ex;
        bcur[t] = ex;
    }
    if (t == 0) bofs[nbuk] = total;
}

__global__ __launch_bounds__(256) void ms_scatter_kernel(const int* __restrict__ src,
                                                         const int* __restrict__ dst,
                                                         int* __restrict__ bcur,
                                                         unsigned* __restrict__ packed,
                                                         int E, int nbuk) {
    __shared__ int cnt[MAXBUK];
    __shared__ int gbase[MAXBUK];
    const int t = threadIdx.x;
    const int e0 = blockIdx.x * 4096;
    const int e1 = min(E, e0 + 4096);
    for (int b = t; b < nbuk; b += 256) cnt[b] = 0;
    __syncthreads();
    for (int e = e0 + t; e < e1; e += 256) atomicAdd(&cnt[dst[e] >> 8], 1);
    __syncthreads();
    for (int b = t; b < nbuk; b += 256) {
        int c = cnt[b];
        gbase[b] = c ? atomicAdd(&bcur[b], c) : 0;
        cnt[b] = 0;
    }
    __syncthreads();
    for (int e = e0 + t; e < e1; e += 256) {
        int d = dst[e];
        int b = d >> 8;
        int r = atomicAdd(&cnt[b], 1);
        packed[gbase[b] + r] = ((unsigned)(d & 255) << 24) | (unsigned)src[e];
    }
}

// 4) csr_fine2: per-node nmeta {base,deg} + dinv; place edge src ids into epack[pos].x.
__global__ __launch_bounds__(256) void csr_fine2_kernel(const unsigned* __restrict__ packed,
                                                        const int* __restrict__ bofs,
                                                        uint2* __restrict__ nmeta,
                                                        float* __restrict__ dinv,
                                                        unsigned* __restrict__ epu, int n) {
    __shared__ int cnt2[NPB];
    __shared__ int cur[NPB];
    const int t = threadIdx.x;
    const int b = blockIdx.x;
    const int node0 = b << 8;
    const int nn = min(NPB, n - node0);
    cnt2[t] = 0;
    __syncthreads();
    const int beg = bofs[b], end = bofs[b + 1];
    for (int i = beg + t; i < end; i += 256) atomicAdd(&cnt2[packed[i] >> 24], 1);
    __syncthreads();
    int c = cnt2[t];
    cur[t] = c;
    __syncthreads();
    for (int o = 1; o < 256; o <<= 1) {        // inclusive scan over 256 local counts
        int u = (t >= o) ? cur[t - o] : 0;
        __syncthreads();
        cur[t] += u;
        __syncthreads();
    }
    const int base = beg + cur[t] - c;          // exclusive
    if (t < nn) {
        nmeta[node0 + t] = make_uint2((unsigned)base, (unsigned)c);
        dinv[node0 + t] = rsqrtf((float)(c + 1));
    }
    __syncthreads();
    cur[t] = base;
    __syncthreads();
    for (int i = beg + t; i < end; i += 256) {
        unsigned u = packed[i];
        int pos = atomicAdd(&cur[u >> 24], 1);
        epu[2 * pos] = u & 0xFFFFFFu;           // epack[pos].x = src
    }
}

// 5) epw: fill epack[j].y = bits(dinv[src_j]).
__global__ __launch_bounds__(256) void epw_kernel(unsigned* __restrict__ epu,
                                                  const float* __restrict__ dinv, int E) {
    int i = blockIdx.x * 256 + threadIdx.x;
    if (i < E) {
        unsigned s = epu[2 * i];
        float w = dinv[s];
        unsigned wb; __builtin_memcpy(&wb, &w, 4);
        epu[2 * i + 1] = wb;
    }
}

// ---------------- GEMM1 (MFMA): H = X * W1, SLICE-MAJOR bf16 out: H[8][N][16ch] ----------------
// Slice-major (32B/node/slice) makes each channel-slice a 3.2MB region that fits one XCD's 4MB L2.

__global__ __launch_bounds__(256) void gemm1_mfma(const void* __restrict__ Xp,
                                                  const unsigned short* __restrict__ WB1,
                                                  unsigned short* __restrict__ H, int nrows,
                                                  const int* __restrict__ flag) {
    __shared__ __align__(16) unsigned short Xs[128 * 136];
    __shared__ __align__(16) unsigned short Cs[128 * 68];
    const int t = threadIdx.x;
    const int r0 = blockIdx.x * 128;
    const int isf32 = *flag;

    if (isf32) {
        const float4* Xg = (const float4*)Xp;
        #pragma unroll
        for (int i = 0; i < 16; ++i) {
            int idx = t + 256 * i;
            int row = idx >> 5, c4 = idx & 31;
            float4 v = {0.f, 0.f, 0.f, 0.f};
            if (r0 + row < nrows) v = Xg[(size_t)(r0 + row) * 32 + c4];
            unsigned lo = (unsigned)f2bf_raw(v.x) | ((unsigned)f2bf_raw(v.y) << 16);
            unsigned hi = (unsigned)f2bf_raw(v.z) | ((unsigned)f2bf_raw(v.w) << 16);
            *reinterpret_cast<uint2*>(&Xs[row * 136 + c4 * 4]) = make_uint2(lo, hi);
        }
    } else {
        const uint4* Xg = (const uint4*)Xp;
        #pragma unroll
        for (int i = 0; i < 8; ++i) {
            int idx = t + 256 * i;
            int row = idx >> 4, c8 = idx & 15;
            uint4 v = {0u, 0u, 0u, 0u};
            if (r0 + row < nrows) v = Xg[(size_t)(r0 + row) * 16 + c8];
            *reinterpret_cast<uint4*>(&Xs[row * 136 + c8 * 8]) = v;
        }
    }
    __syncthreads();

    const int lane = t & 63, w = t >> 6;
    const int m0 = w * 32;
    short8 a[2][4];
    #pragma unroll
    for (int rt = 0; rt < 2; ++rt)
        #pragma unroll
        for (int kk = 0; kk < 4; ++kk)
            a[rt][kk] = *reinterpret_cast<const short8*>(
                &Xs[(m0 + rt * 16 + (lane & 15)) * 136 + kk * 32 + (lane >> 4) * 8]);

    for (int p = 0; p < 2; ++p) {
        short8 b[4][4];
        #pragma unroll
        for (int n = 0; n < 4; ++n)
            #pragma unroll
            for (int kk = 0; kk < 4; ++kk)
                b[n][kk] = *reinterpret_cast<const short8*>(
                    WB1 + (size_t)(((p * 4 + n) * 4 + kk) * 64 + lane) * 8);
        f32x4 acc[2][4];
        #pragma unroll
        for (int rt = 0; rt < 2; ++rt)
            #pragma unroll
            for (int n = 0; n < 4; ++n) {
                acc[rt][n] = (f32x4){0.f, 0.f, 0.f, 0.f};
                #pragma unroll
                for (int kk = 0; kk < 4; ++kk)
                    acc[rt][n] = __builtin_amdgcn_mfma_f32_16x16x32_bf16(
                        a[rt][kk], b[n][kk], acc[rt][n], 0, 0, 0);
            }
        if (p) __syncthreads();
        #pragma unroll
        for (int rt = 0; rt < 2; ++rt)
            #pragma unroll
            for (int n = 0; n < 4; ++n)
                #pragma unroll
                for (int r = 0; r < 4; ++r) {
                    int row = m0 + rt * 16 + (lane >> 4) * 4 + r;
                    Cs[row * 68 + n * 16 + (lane & 15)] = f2bf_raw(acc[rt][n][r]);
                }
        __syncthreads();
        #pragma unroll
        for (int i = 0; i < 8; ++i) {
            int idx = t + 256 * i;
            int row = idx >> 4, c4 = idx & 15;
            if (r0 + row < nrows) {
                uint2 v = *reinterpret_cast<const uint2*>(&Cs[row * 68 + c4 * 4]);
                int slice = p * 4 + (c4 >> 2);   // global ch = p*64 + c4*4; slice = ch>>4
                *reinterpret_cast<uint2*>(
                    H + ((size_t)slice * nrows + (r0 + row)) * 16 + (c4 & 3) * 4) = v;
            }
        }
        if (!p) __syncthreads();
    }
}

// ---------------- Aggregation v6 (layer 1): XCD channel-sliced ----------------
// slice = blockIdx & 7 -> lands on one XCD (round-robin dispatch); that XCD's gathers stay
// within a 3.2MB slice that FITS its 4MB L2. Wave per node: 16 edge-groups x 4 subs (8B/lane).
// Edge stream epack = {src, w_bits} (one 8B load/edge). Tail round is exec-predicated (no pads).

__global__ __launch_bounds__(256) void agg128_v6(const unsigned short* __restrict__ Hs,
                                                 const uint2* __restrict__ nmeta,
                                                 const uint2* __restrict__ epack,
                                                 const float* __restrict__ biasf,
                                                 unsigned short* __restrict__ Gs, int n) {
    const int lane = threadIdx.x & 63;
    const int g = lane >> 2;          // 16 edge groups
    const int sub = lane & 3;         // 8B chunk of the 32B slice-row
    const int slice = blockIdx.x & 7;
    const int node = (blockIdx.x >> 3) * 4 + (threadIdx.x >> 6);
    if (node >= n) return;

    const uint2* Hp = (const uint2*)(Hs + (size_t)slice * n * 16);
    uint2 vself = Hp[(unsigned)node * 4u + (unsigned)sub];

    const uint2 meta = nmeta[node];
    const int base = (int)meta.x;
    const int cnt = (int)meta.y;
    const int end = base + cnt;
    const float di = rsqrtf((float)(cnt + 1));

    const float ws = (g == 0) ? di * di : 0.f;
    f32x2 acc0 = {ws * lo_f(vself.x), ws * hi_f(vself.x)};
    f32x2 acc1 = {ws * lo_f(vself.y), ws * hi_f(vself.y)};

    int j = base;
    for (; j + 15 < end; j += 16) {
        uint2 ep = epack[j + g];
        float w; __builtin_memcpy(&w, &ep.y, 4);
        w *= di;
        uint2 v = Hp[ep.x * 4u + (unsigned)sub];
        acc0 += (f32x2){lo_f(v.x), hi_f(v.x)} * (f32x2){w, w};
        acc1 += (f32x2){lo_f(v.y), hi_f(v.y)} * (f32x2){w, w};
    }
    if (j + g < end) {                 // tail: groups >= remaining simply don't load
        uint2 ep = epack[j + g];
        float w; __builtin_memcpy(&w, &ep.y, 4);
        w *= di;
        uint2 v = Hp[ep.x * 4u + (unsigned)sub];
        acc0 += (f32x2){lo_f(v.x), hi_f(v.x)} * (f32x2){w, w};
        acc1 += (f32x2){lo_f(v.y), hi_f(v.y)} * (f32x2){w, w};
    }

    float a4[4] = {acc0.x, acc0.y, acc1.x, acc1.y};
    #pragma unroll
    for (int i = 0; i < 4; ++i) {      // reduce over the 16 groups (lane bits 2..5)
        a4[i] += __shfl_xor(a4[i], 4, 64);
        a4[i] += __shfl_xor(a4[i], 8, 64);
        a4[i] += __shfl_xor(a4[i], 16, 64);
        a4[i] += __shfl_xor(a4[i], 32, 64);
    }

    if (g == 0) {                      // lanes 0..3 write the 32B slice-row
        float4 b = ((const float4*)biasf)[slice * 4 + sub];
        a4[0] = fmaxf(a4[0] + b.x, 0.f);
        a4[1] = fmaxf(a4[1] + b.y, 0.f);
        a4[2] = fmaxf(a4[2] + b.z, 0.f);
        a4[3] = fmaxf(a4[3] + b.w, 0.f);
        uint2 o;
        o.x = (unsigned)f2bf_raw(a4[0]) | ((unsigned)f2bf_raw(a4[1]) << 16);
        o.y = (unsigned)f2bf_raw(a4[2]) | ((unsigned)f2bf_raw(a4[3]) << 16);
        ((uint2*)(Gs + (size_t)slice * n * 16))[(unsigned)node * 4u + (unsigned)sub] = o;
    }
}

// ---------------- GEMM2b (MFMA): T[nrows x 64] = G1 * W2 (G1 slice-major in), row-major T out ----

__global__ __launch_bounds__(256) void gemm2b_mfma(const unsigned short* __restrict__ Gsm,
                                                   const unsigned short* __restrict__ WB2,
                                                   unsigned short* __restrict__ T, int nrows) {
    __shared__ __align__(16) unsigned short Xs[128 * 136];
    __shared__ __align__(16) unsigned short Cs[128 * 68];
    const int t = threadIdx.x;
    const int r0 = blockIdx.x * 128;

    // slice-major load: G[slice][row][16ch]; per (row,slice) two uint4s (32B)
    const uint4* Gg = (const uint4*)Gsm;
    #pragma unroll
    for (int i = 0; i < 8; ++i) {
        int idx = t + 256 * i;
        int row = idx >> 4, q = idx & 15;
        int slice = q >> 1, h = q & 1;
        uint4 v = {0u, 0u, 0u, 0u};
        if (r0 + row < nrows) v = Gg[((size_t)slice * nrows + (r0 + row)) * 2 + h];
        *reinterpret_cast<uint4*>(&Xs[row * 136 + slice * 16 + h * 8]) = v;
    }
    __syncthreads();

    const int lane = t & 63, w = t >> 6;
    const int m0 = w * 32;
    short8 a[2][4];
    #pragma unroll
    for (int rt = 0; rt < 2; ++rt)
        #pragma unroll
        for (int kk = 0; kk < 4; ++kk)
            a[rt][kk] = *reinterpret_cast<const short8*>(
                &Xs[(m0 + rt * 16 + (lane & 15)) * 136 + kk * 32 + (lane >> 4) * 8]);

    short8 b[4][4];
    #pragma unroll
    for (int n = 0; n < 4; ++n)
        #pragma unroll
        for (int kk = 0; kk < 4; ++kk)
            b[n][kk] = *reinterpret_cast<const short8*>(
                WB2 + (size_t)((n * 4 + kk) * 64 + lane) * 8);

    f32x4 acc[2][4];
    #pragma unroll
    for (int rt = 0; rt < 2; ++rt)
        #pragma unroll
        for (int n = 0; n < 4; ++n) {
            acc[rt][n] = (f32x4){0.f, 0.f, 0.f, 0.f};
            #pragma unroll
            for (int kk = 0; kk < 4; ++kk)
                acc[rt][n] = __builtin_amdgcn_mfma_f32_16x16x32_bf16(
                    a[rt][kk], b[n][kk], acc[rt][n], 0, 0, 0);
        }

    __syncthreads();
    #pragma unroll
    for (int rt = 0; rt < 2; ++rt)
        #pragma unroll
        for (int n = 0; n < 4; ++n)
            #pragma unroll
            for (int r = 0; r < 4; ++r) {
                int row = m0 + rt * 16 + (lane >> 4) * 4 + r;
                Cs[row * 68 + n * 16 + (lane & 15)] = f2bf_raw(acc[rt][n][r]);
            }
    __syncthreads();
    #pragma unroll
    for (int i = 0; i < 8; ++i) {
        int idx = t + 256 * i;
        int row = idx >> 4, c4 = idx & 15;
        if (r0 + row < nrows) {
            uint2 v = *reinterpret_cast<const uint2*>(&Cs[row * 68 + c4 * 4]);
            *reinterpret_cast<uint2*>(T + (size_t)(r0 + row) * 64 + c4 * 4) = v;
        }
    }
}

// ---------------- Aggregation 2 + bias + log_softmax (64 ch, row-major T) ----------------

__device__ __forceinline__ void acc8v(f32x2* acc, uint4 v, float w) {
    f32x2 wv = {w, w};
    acc[0] += (f32x2){lo_f(v.x), hi_f(v.x)} * wv;
    acc[1] += (f32x2){lo_f(v.y), hi_f(v.y)} * wv;
    acc[2] += (f32x2){lo_f(v.z), hi_f(v.z)} * wv;
    acc[3] += (f32x2){lo_f(v.w), hi_f(v.w)} * wv;
}

__global__ __launch_bounds__(128) void agg64_final(const uint4* __restrict__ T4,
                                                   const uint2* __restrict__ nmeta,
                                                   const uint2* __restrict__ epack,
                                                   const float* __restrict__ b2f,
                                                   void* __restrict__ OUTv, int n,
                                                   const int* __restrict__ flag) {
    const int lane = threadIdx.x & 63;
    const int g = lane >> 3;
    const int sub = lane & 7;
    const int node = blockIdx.x * 2 + (threadIdx.x >> 6);
    if (node >= n) return;
    const int outf32 = *flag;

    const unsigned selfoff = ((unsigned)node << 3) + (unsigned)sub;
    uint4 vself = T4[selfoff];

    const uint2 meta = nmeta[node];
    const int base = (int)meta.x;
    const int cnt = (int)meta.y;
    const int end = base + cnt;
    const float di = rsqrtf((float)(cnt + 1));

    f32x2 acc[4];
    {
        const float ws = (g == 0) ? di * di : 0.f;
        acc[0] = (f32x2){ws * lo_f(vself.x), ws * hi_f(vself.x)};
        acc[1] = (f32x2){ws * lo_f(vself.y), ws * hi_f(vself.y)};
        acc[2] = (f32x2){ws * lo_f(vself.z), ws * hi_f(vself.z)};
        acc[3] = (f32x2){ws * lo_f(vself.w), ws * hi_f(vself.w)};
    }

    int j = base;
    for (; j + 15 < end; j += 16) {          // 16 edges, 2 gathers per lane in flight
        uint2 e0 = epack[j + g];
        uint2 e1 = epack[j + 8 + g];
        uint4 v0 = T4[(e0.x << 3) + (unsigned)sub];
        uint4 v1 = T4[(e1.x << 3) + (unsigned)sub];
        float w0, w1;
        __builtin_memcpy(&w0, &e0.y, 4);
        __builtin_memcpy(&w1, &e1.y, 4);
        acc8v(acc, v0, di * w0);
        acc8v(acc, v1, di * w1);
    }
    for (; j + 7 < end; j += 8) {            // 8 edges
        uint2 e0 = epack[j + g];
        uint4 v0 = T4[(e0.x << 3) + (unsigned)sub];
        float w0; __builtin_memcpy(&w0, &e0.y, 4);
        acc8v(acc, v0, di * w0);
    }
    if (j + g < end) {                       // tail (<8 edges), group-predicated
        uint2 e0 = epack[j + g];
        uint4 v0 = T4[(e0.x << 3) + (unsigned)sub];
        float w0; __builtin_memcpy(&w0, &e0.y, 4);
        acc8v(acc, v0, di * w0);
    }

    float a8[8];
    #pragma unroll
    for (int i = 0; i < 4; ++i) { a8[2 * i] = acc[i].x; a8[2 * i + 1] = acc[i].y; }
    #pragma unroll
    for (int i = 0; i < 8; ++i) {            // combine the 8 edge-groups
        a8[i] += __shfl_xor(a8[i], 8, 64);
        a8[i] += __shfl_xor(a8[i], 16, 64);
        a8[i] += __shfl_xor(a8[i], 32, 64);
    }

    if (g == 0) {                            // lanes 0..7 hold the full 64-ch row
        const float4* b4 = (const float4*)b2f;
        float4 blo = b4[sub * 2], bhi = b4[sub * 2 + 1];
        a8[0] += blo.x; a8[1] += blo.y; a8[2] += blo.z; a8[3] += blo.w;
        a8[4] += bhi.x; a8[5] += bhi.y; a8[6] += bhi.z; a8[7] += bhi.w;

        float m = fmaxf(fmaxf(fmaxf(a8[0], a8[1]), fmaxf(a8[2], a8[3])),
                        fmaxf(fmaxf(a8[4], a8[5]), fmaxf(a8[6], a8[7])));
        m = fmaxf(m, __shfl_xor(m, 1, 64));
        m = fmaxf(m, __shfl_xor(m, 2, 64));
        m = fmaxf(m, __shfl_xor(m, 4, 64));
        float s = __expf(a8[0] - m) + __expf(a8[1] - m) + __expf(a8[2] - m) + __expf(a8[3] - m) +
                  __expf(a8[4] - m) + __expf(a8[5] - m) + __expf(a8[6] - m) + __expf(a8[7] - m);
        s += __shfl_xor(s, 1, 64);
        s += __shfl_xor(s, 2, 64);
        s += __shfl_xor(s, 4, 64);
        const float lse = m + __logf(s);

        if (outf32) {
            float4* Of = (float4*)OUTv;
            float4 o0 = {a8[0] - lse, a8[1] - lse, a8[2] - lse, a8[3] - lse};
            float4 o1 = {a8[4] - lse, a8[5] - lse, a8[6] - lse, a8[7] - lse};
            Of[(size_t)node * 16 + sub * 2] = o0;
            Of[(size_t)node * 16 + sub * 2 + 1] = o1;
        } else {
            uint4 o;
            o.x = (unsigned)f2bf_raw(a8[0] - lse) | ((unsigned)f2bf_raw(a8[1] - lse) << 16);
            o.y = (unsigned)f2bf_raw(a8[2] - lse) | ((unsigned)f2bf_raw(a8[3] - lse) << 16);
            o.z = (unsigned)f2bf_raw(a8[4] - lse) | ((unsigned)f2bf_raw(a8[5] - lse) << 16);
            o.w = (unsigned)f2bf_raw(a8[6] - lse) | ((unsigned)f2bf_raw(a8[7] - lse) << 16);
            ((uint4*)OUTv)[(size_t)node * 8 + sub] = o;
        }
    }
}

// ---------------- launch ----------------

extern "C" void kernel_launch(void* const* d_in, const int* in_sizes, int n_in,
                              void* d_out, int out_size, void* d_ws, size_t ws_size,
                              hipStream_t stream) {
    const void* x  = d_in[0];
    const int*  ei = (const int*)d_in[1];
    const void* W1 = d_in[2];
    const void* b1 = d_in[3];
    const void* W2 = d_in[4];
    const void* b2 = d_in[5];

    const int N = in_sizes[0] / 128;
    const int E = in_sizes[1] / 2;
    const int* src = ei;
    const int* dst = ei + E;
    const int NBUK = (N + NPB - 1) / NPB;     // 391 for N=100K

    char* p = (char*)d_ws;
    auto alloc = [&](size_t bytes) { char* q = p; p += (bytes + 255) & ~255ull; return q; };
    int*   flag   = (int*)  alloc(4);
    uint2* nmeta  = (uint2*)alloc((size_t)N * 8);
    float* dinv   = (float*)alloc((size_t)N * 4);
    int*   bktcnt = (int*)  alloc((size_t)NBUK * 4);
    int*   bofs   = (int*)  alloc((size_t)(NBUK + 1) * 4);
    int*   bcur   = (int*)  alloc((size_t)NBUK * 4);
    float* b1f    = (float*)alloc(128 * 4);
    float* b2f    = (float*)alloc(64 * 4);
    unsigned short* WB1 = (unsigned short*)alloc(16384 * 2);
    unsigned short* WB2 = (unsigned short*)alloc(8192 * 2);
    unsigned* big = (unsigned*)alloc((size_t)N * 128 * 2);   // H slice-major (25.6 MB), later T (12.8 MB)
    unsigned* packed = (unsigned*)d_out;          // 6.4 MB scratch in d_out (dead after csr_fine2)
    uint2*    epack  = (uint2*)d_in[1];           // {src, w_bits}; overwrites src+dst (dead after ms_scatter)
    unsigned short* Gs = (unsigned short*)d_in[0];// G1 slice-major into x's buffer (x dead after gemm1)
    unsigned short* T = (unsigned short*)big;     // T (row-major) overwrites H (dead after agg1)
    (void)ws_size; (void)n_in; (void)out_size;

    hipMemsetAsync(bktcnt, 0, (size_t)NBUK * 4, stream);
    sniff_kernel<<<1, 1024, 0, stream>>>((const unsigned short*)W1, in_sizes[2], flag);
    prep_kernel<<<97, 256, 0, stream>>>(W1, W2, b1, b2, WB1, WB2, b1f, b2f, flag);
    const int MSB = (E + 4095) / 4096;
    ms_count_kernel<<<MSB, 256, 0, stream>>>(dst, bktcnt, E, NBUK);
    bscan_kernel<<<1, 1024, 0, stream>>>(bktcnt, bofs, bcur, NBUK, E);
    ms_scatter_kernel<<<MSB, 256, 0, stream>>>(src, dst, bcur, packed, E, NBUK);
    csr_fine2_kernel<<<NBUK, 256, 0, stream>>>(packed, bofs, nmeta, dinv, (unsigned*)epack, N);
    epw_kernel<<<(E + 255) / 256, 256, 0, stream>>>((unsigned*)epack, dinv, E);

    const int GB = (N + 127) / 128;
    gemm1_mfma<<<GB, 256, 0, stream>>>(x, WB1, (unsigned short*)big, N, flag);
    agg128_v6<<<8 * ((N + 3) / 4), 256, 0, stream>>>((const unsigned short*)big, nmeta, epack,
                                                     b1f, Gs, N);
    gemm2b_mfma<<<GB, 256, 0, stream>>>(Gs, WB2, T, N);
    agg64_final<<<(N + 1) / 2, 128, 0, stream>>>((const uint4*)T, nmeta, epack, b2f, d_out, N, flag);
}

// Round 7
// 312.932 us; speedup vs baseline: 1.5599x; 1.5599x over previous
//
#include <hip/hip_runtime.h>
#include <hip/hip_bf16.h>

typedef __hip_bfloat16 bf16;
typedef short short8 __attribute__((ext_vector_type(8)));
typedef float f32x4 __attribute__((ext_vector_type(4)));
typedef float f32x2 __attribute__((ext_vector_type(2)));

#define NPB 256          // nodes per bucket (coarse radix = dst>>8)
#define MAXBUK 1024      // supports N <= 262144

__device__ __forceinline__ float bf2f_raw(unsigned short u) {
    unsigned x = ((unsigned)u) << 16; float f; __builtin_memcpy(&f, &x, 4); return f;
}
__device__ __forceinline__ unsigned short f2bf_raw(float f) {   // RNE
    unsigned u; __builtin_memcpy(&u, &f, 4);
    u += 0x7FFFu + ((u >> 16) & 1u);
    return (unsigned short)(u >> 16);
}
__device__ __forceinline__ float lo_f(unsigned u) {
    unsigned x = u << 16; float f; __builtin_memcpy(&f, &x, 4); return f;
}
__device__ __forceinline__ float hi_f(unsigned u) {
    unsigned x = u & 0xffff0000u; float f; __builtin_memcpy(&f, &x, 4); return f;
}

// ---------------- prep (fused sniff + weight repack + bias conv + bktcnt zero) ----------------
// Every block sniffs the SAME 2048-short sample of W1 -> identical local isf32 verdict;
// block 0 publishes flag for gemm1/agg64. Tail thread range zeroes bktcnt (replaces memset).

__global__ __launch_bounds__(256) void prep_kernel(const unsigned short* __restrict__ W1s,
                                                   const void* __restrict__ W1p,
                                                   const void* __restrict__ W2p,
                                                   const void* __restrict__ b1p,
                                                   const void* __restrict__ b2p,
                                                   unsigned short* __restrict__ WB1,
                                                   unsigned short* __restrict__ WB2,
                                                   float* __restrict__ b1f,
                                                   float* __restrict__ b2f,
                                                   int* __restrict__ flag,
                                                   int* __restrict__ bktcnt,
                                                   int nshorts, int nbuk) {
    __shared__ int red[256];
    const int tt = threadIdx.x;
    const int sample = min(nshorts, 2048);
    int c = 0;
    for (int i = tt; i < sample; i += 256) {
        unsigned e = (W1s[i] >> 7) & 0xFFu;
        if (e >= 140u || (e >= 1u && e <= 40u)) c++;
    }
    red[tt] = c;
    __syncthreads();
    for (int o = 128; o > 0; o >>= 1) {
        if (tt < o) red[tt] += red[tt + o];
        __syncthreads();
    }
    const int isf32 = (red[0] > sample / 8) ? 1 : 0;
    if (blockIdx.x == 0 && tt == 0) *flag = isf32;

    const int t = blockIdx.x * 256 + tt;
    const int T1 = 16384, T2 = 8192;
    if (t < T1) {
        int j = t & 7, l = (t >> 3) & 63, f = t >> 9;
        int n = f >> 2, kk = f & 3;
        int k = kk * 32 + (l >> 4) * 8 + j;
        int col = n * 16 + (l & 15);
        WB1[t] = isf32 ? f2bf_raw(((const float*)W1p)[k * 128 + col])
                       : ((const unsigned short*)W1p)[k * 128 + col];
    } else if (t < T1 + T2) {
        int o = t - T1;
        int j = o & 7, l = (o >> 3) & 63, f = o >> 9;
        int n = f >> 2, kk = f & 3;
        int k = kk * 32 + (l >> 4) * 8 + j;
        int col = n * 16 + (l & 15);
        WB2[o] = isf32 ? f2bf_raw(((const float*)W2p)[k * 64 + col])
                       : ((const unsigned short*)W2p)[k * 64 + col];
    } else if (t < T1 + T2 + 128) {
        int o = t - T1 - T2;
        b1f[o] = isf32 ? ((const float*)b1p)[o] : bf2f_raw(((const unsigned short*)b1p)[o]);
    } else if (t < T1 + T2 + 192) {
        int o = t - T1 - T2 - 128;
        b2f[o] = isf32 ? ((const float*)b2p)[o] : bf2f_raw(((const unsigned short*)b2p)[o]);
    } else if (t < T1 + T2 + 192 + nbuk) {
        bktcnt[t - T1 - T2 - 192] = 0;
    }
}

// ---------------- CSR build, bucket-granular ----------------

__global__ __launch_bounds__(256) void ms_count_kernel(const int* __restrict__ dst,
                                                       int* __restrict__ bktcnt,
                                                       int E, int nbuk) {
    __shared__ int cnt[MAXBUK];
    const int t = threadIdx.x;
    const int e0 = blockIdx.x * 4096;
    const int e1 = min(E, e0 + 4096);
    for (int b = t; b < nbuk; b += 256) cnt[b] = 0;
    __syncthreads();
    for (int e = e0 + t; e < e1; e += 256) atomicAdd(&cnt[dst[e] >> 8], 1);
    __syncthreads();
    for (int b = t; b < nbuk; b += 256) {
        int c = cnt[b];
        if (c) atomicAdd(&bktcnt[b], c);
    }
}

__global__ __launch_bounds__(1024) void bscan_kernel(const int* __restrict__ bktcnt,
                                                     int* __restrict__ bofs,
                                                     int* __restrict__ bcur,
                                                     int nbuk, int total) {
    __shared__ int ps[1024];
    const int t = threadIdx.x;
    int v = (t < nbuk) ? bktcnt[t] : 0;
    ps[t] = v;
    __syncthreads();
    for (int o = 1; o < 1024; o <<= 1) {
        int u = (t >= o) ? ps[t - o] : 0;
        __syncthreads();
        ps[t] += u;
        __syncthreads();
    }
    if (t < nbuk) {
        int ex = ps[t] - v;
        bofs[t] = ex;
        bcur[t] = ex;
    }
    if (t == 0) bofs[nbuk] = total;
}

__global__ __launch_bounds__(256) void ms_scatter_kernel(const int* __restrict__ src,
                                                         const int* __restrict__ dst,
                                                         int* __restrict__ bcur,
                                                         unsigned* __restrict__ packed,
                                                         int E, int nbuk) {
    __shared__ int cnt[MAXBUK];
    __shared__ int gbase[MAXBUK];
    const int t = threadIdx.x;
    const int e0 = blockIdx.x * 4096;
    const int e1 = min(E, e0 + 4096);
    for (int b = t; b < nbuk; b += 256) cnt[b] = 0;
    __syncthreads();
    for (int e = e0 + t; e < e1; e += 256) atomicAdd(&cnt[dst[e] >> 8], 1);
    __syncthreads();
    for (int b = t; b < nbuk; b += 256) {
        int c = cnt[b];
        gbase[b] = c ? atomicAdd(&bcur[b], c) : 0;
        cnt[b] = 0;
    }
    __syncthreads();
    for (int e = e0 + t; e < e1; e += 256) {
        int d = dst[e];
        int b = d >> 8;
        int r = atomicAdd(&cnt[b], 1);
        packed[gbase[b] + r] = ((unsigned)(d & 255) << 24) | (unsigned)src[e];
    }
}

// 4) csr_fine2: per-node nmeta {base,deg} + dinv; place edge src ids into epack[pos].x.
__global__ __launch_bounds__(256) void csr_fine2_kernel(const unsigned* __restrict__ packed,
                                                        const int* __restrict__ bofs,
                                                        uint2* __restrict__ nmeta,
                                                        float* __restrict__ dinv,
                                                        unsigned* __restrict__ epu, int n) {
    __shared__ int cnt2[NPB];
    __shared__ int cur[NPB];
    const int t = threadIdx.x;
    const int b = blockIdx.x;
    const int node0 = b << 8;
    const int nn = min(NPB, n - node0);
    cnt2[t] = 0;
    __syncthreads();
    const int beg = bofs[b], end = bofs[b + 1];
    for (int i = beg + t; i < end; i += 256) atomicAdd(&cnt2[packed[i] >> 24], 1);
    __syncthreads();
    int c = cnt2[t];
    cur[t] = c;
    __syncthreads();
    for (int o = 1; o < 256; o <<= 1) {        // inclusive scan over 256 local counts
        int u = (t >= o) ? cur[t - o] : 0;
        __syncthreads();
        cur[t] += u;
        __syncthreads();
    }
    const int base = beg + cur[t] - c;          // exclusive
    if (t < nn) {
        nmeta[node0 + t] = make_uint2((unsigned)base, (unsigned)c);
        dinv[node0 + t] = rsqrtf((float)(c + 1));
    }
    __syncthreads();
    cur[t] = base;
    __syncthreads();
    for (int i = beg + t; i < end; i += 256) {
        unsigned u = packed[i];
        int pos = atomicAdd(&cur[u >> 24], 1);
        epu[2 * pos] = u & 0xFFFFFFu;           // epack[pos].x = src
    }
}

// 5) epw: fill epack[j].y = bits(dinv[src_j]).
__global__ __launch_bounds__(256) void epw_kernel(unsigned* __restrict__ epu,
                                                  const float* __restrict__ dinv, int E) {
    int i = blockIdx.x * 256 + threadIdx.x;
    if (i < E) {
        unsigned s = epu[2 * i];
        float w = dinv[s];
        unsigned wb; __builtin_memcpy(&wb, &w, 4);
        epu[2 * i + 1] = wb;
    }
}

// ---------------- GEMM1 (MFMA): H[nrows x 128] = X * W1, row-major bf16 out ----------------

__global__ __launch_bounds__(256) void gemm1_mfma(const void* __restrict__ Xp,
                                                  const unsigned short* __restrict__ WB1,
                                                  unsigned short* __restrict__ H, int nrows,
                                                  const int* __restrict__ flag) {
    __shared__ __align__(16) unsigned short Xs[128 * 136];
    __shared__ __align__(16) unsigned short Cs[128 * 68];
    const int t = threadIdx.x;
    const int r0 = blockIdx.x * 128;
    const int isf32 = *flag;

    if (isf32) {
        const float4* Xg = (const float4*)Xp;
        #pragma unroll
        for (int i = 0; i < 16; ++i) {
            int idx = t + 256 * i;
            int row = idx >> 5, c4 = idx & 31;
            float4 v = {0.f, 0.f, 0.f, 0.f};
            if (r0 + row < nrows) v = Xg[(size_t)(r0 + row) * 32 + c4];
            unsigned lo = (unsigned)f2bf_raw(v.x) | ((unsigned)f2bf_raw(v.y) << 16);
            unsigned hi = (unsigned)f2bf_raw(v.z) | ((unsigned)f2bf_raw(v.w) << 16);
            *reinterpret_cast<uint2*>(&Xs[row * 136 + c4 * 4]) = make_uint2(lo, hi);
        }
    } else {
        const uint4* Xg = (const uint4*)Xp;
        #pragma unroll
        for (int i = 0; i < 8; ++i) {
            int idx = t + 256 * i;
            int row = idx >> 4, c8 = idx & 15;
            uint4 v = {0u, 0u, 0u, 0u};
            if (r0 + row < nrows) v = Xg[(size_t)(r0 + row) * 16 + c8];
            *reinterpret_cast<uint4*>(&Xs[row * 136 + c8 * 8]) = v;
        }
    }
    __syncthreads();

    const int lane = t & 63, w = t >> 6;
    const int m0 = w * 32;
    short8 a[2][4];
    #pragma unroll
    for (int rt = 0; rt < 2; ++rt)
        #pragma unroll
        for (int kk = 0; kk < 4; ++kk)
            a[rt][kk] = *reinterpret_cast<const short8*>(
                &Xs[(m0 + rt * 16 + (lane & 15)) * 136 + kk * 32 + (lane >> 4) * 8]);

    for (int p = 0; p < 2; ++p) {
        short8 b[4][4];
        #pragma unroll
        for (int n = 0; n < 4; ++n)
            #pragma unroll
            for (int kk = 0; kk < 4; ++kk)
                b[n][kk] = *reinterpret_cast<const short8*>(
                    WB1 + (size_t)(((p * 4 + n) * 4 + kk) * 64 + lane) * 8);
        f32x4 acc[2][4];
        #pragma unroll
        for (int rt = 0; rt < 2; ++rt)
            #pragma unroll
            for (int n = 0; n < 4; ++n) {
                acc[rt][n] = (f32x4){0.f, 0.f, 0.f, 0.f};
                #pragma unroll
                for (int kk = 0; kk < 4; ++kk)
                    acc[rt][n] = __builtin_amdgcn_mfma_f32_16x16x32_bf16(
                        a[rt][kk], b[n][kk], acc[rt][n], 0, 0, 0);
            }
        if (p) __syncthreads();
        #pragma unroll
        for (int rt = 0; rt < 2; ++rt)
            #pragma unroll
            for (int n = 0; n < 4; ++n)
                #pragma unroll
                for (int r = 0; r < 4; ++r) {
                    int row = m0 + rt * 16 + (lane >> 4) * 4 + r;
                    Cs[row * 68 + n * 16 + (lane & 15)] = f2bf_raw(acc[rt][n][r]);
                }
        __syncthreads();
        #pragma unroll
        for (int i = 0; i < 8; ++i) {
            int idx = t + 256 * i;
            int row = idx >> 4, c4 = idx & 15;
            if (r0 + row < nrows) {
                uint2 v = *reinterpret_cast<const uint2*>(&Cs[row * 68 + c4 * 4]);
                *reinterpret_cast<uint2*>(H + (size_t)(r0 + row) * 128 + p * 64 + c4 * 4) = v;
            }
        }
        if (!p) __syncthreads();
    }
}

// ---------------- Aggregation v7 (layer 1): wave-per-node, 16/8/4/tail, epack, di-factored ----
// out = di * (sum_j w_j * h_src_j  +  di * h_self); per-edge di-multiply eliminated.

__device__ __forceinline__ void acc8v(f32x2* acc, uint4 v, float w) {
    f32x2 wv = {w, w};
    acc[0] += (f32x2){lo_f(v.x), hi_f(v.x)} * wv;
    acc[1] += (f32x2){lo_f(v.y), hi_f(v.y)} * wv;
    acc[2] += (f32x2){lo_f(v.z), hi_f(v.z)} * wv;
    acc[3] += (f32x2){lo_f(v.w), hi_f(v.w)} * wv;
}
__device__ __forceinline__ float epw_f(uint2 e) {
    float w; __builtin_memcpy(&w, &e.y, 4); return w;
}

__global__ __launch_bounds__(128) void agg128_v7(const uint4* __restrict__ H4,
                                                 const uint2* __restrict__ nmeta,
                                                 const uint2* __restrict__ epack,
                                                 const float* __restrict__ biasf,
                                                 uint4* __restrict__ G4, int n) {
    const int lane = threadIdx.x & 63;
    const int g = lane >> 4;
    const int sub = lane & 15;
    const int node = blockIdx.x * 2 + (threadIdx.x >> 6);
    if (node >= n) return;

    const unsigned selfoff = ((unsigned)node << 4) + (unsigned)sub;
    uint4 vself = H4[selfoff];

    const uint2 meta = nmeta[node];
    const int base = (int)meta.x;
    const int cnt = (int)meta.y;
    const int end = base + cnt;
    const float di = rsqrtf((float)(cnt + 1));

    f32x2 acc[4];
    {
        const float ws = (g == 0) ? di : 0.f;      // di-factored: self carries di, not di^2
        acc[0] = (f32x2){ws * lo_f(vself.x), ws * hi_f(vself.x)};
        acc[1] = (f32x2){ws * lo_f(vself.y), ws * hi_f(vself.y)};
        acc[2] = (f32x2){ws * lo_f(vself.z), ws * hi_f(vself.z)};
        acc[3] = (f32x2){ws * lo_f(vself.w), ws * hi_f(vself.w)};
    }

    int j = base;
    for (; j + 15 < end; j += 16) {
        uint2 e0 = epack[j + g];
        uint2 e1 = epack[j + 4 + g];
        uint2 e2 = epack[j + 8 + g];
        uint2 e3 = epack[j + 12 + g];
        uint4 v0 = H4[(e0.x << 4) + (unsigned)sub];
        uint4 v1 = H4[(e1.x << 4) + (unsigned)sub];
        uint4 v2 = H4[(e2.x << 4) + (unsigned)sub];
        uint4 v3 = H4[(e3.x << 4) + (unsigned)sub];
        acc8v(acc, v0, epw_f(e0));
        acc8v(acc, v1, epw_f(e1));
        acc8v(acc, v2, epw_f(e2));
        acc8v(acc, v3, epw_f(e3));
    }
    for (; j + 7 < end; j += 8) {
        uint2 e0 = epack[j + g];
        uint2 e1 = epack[j + 4 + g];
        uint4 v0 = H4[(e0.x << 4) + (unsigned)sub];
        uint4 v1 = H4[(e1.x << 4) + (unsigned)sub];
        acc8v(acc, v0, epw_f(e0));
        acc8v(acc, v1, epw_f(e1));
    }
    for (; j + 3 < end; j += 4) {
        uint2 e0 = epack[j + g];
        uint4 v0 = H4[(e0.x << 4) + (unsigned)sub];
        acc8v(acc, v0, epw_f(e0));
    }
    if (j + g < end) {
        uint2 e0 = epack[j + g];
        uint4 v0 = H4[(e0.x << 4) + (unsigned)sub];
        acc8v(acc, v0, epw_f(e0));
    }

    float a8[8];
    #pragma unroll
    for (int i = 0; i < 4; ++i) { a8[2 * i] = acc[i].x; a8[2 * i + 1] = acc[i].y; }
    #pragma unroll
    for (int i = 0; i < 8; ++i) {
        a8[i] += __shfl_xor(a8[i], 16, 64);
        a8[i] += __shfl_xor(a8[i], 32, 64);
    }

    if (g == 0) {
        const float4* b4 = (const float4*)biasf;
        float4 blo = b4[sub * 2], bhi = b4[sub * 2 + 1];
        a8[0] = fmaxf(fmaf(di, a8[0], blo.x), 0.f);
        a8[1] = fmaxf(fmaf(di, a8[1], blo.y), 0.f);
        a8[2] = fmaxf(fmaf(di, a8[2], blo.z), 0.f);
        a8[3] = fmaxf(fmaf(di, a8[3], blo.w), 0.f);
        a8[4] = fmaxf(fmaf(di, a8[4], bhi.x), 0.f);
        a8[5] = fmaxf(fmaf(di, a8[5], bhi.y), 0.f);
        a8[6] = fmaxf(fmaf(di, a8[6], bhi.z), 0.f);
        a8[7] = fmaxf(fmaf(di, a8[7], bhi.w), 0.f);
        uint4 o;
        o.x = (unsigned)f2bf_raw(a8[0]) | ((unsigned)f2bf_raw(a8[1]) << 16);
        o.y = (unsigned)f2bf_raw(a8[2]) | ((unsigned)f2bf_raw(a8[3]) << 16);
        o.z = (unsigned)f2bf_raw(a8[4]) | ((unsigned)f2bf_raw(a8[5]) << 16);
        o.w = (unsigned)f2bf_raw(a8[6]) | ((unsigned)f2bf_raw(a8[7]) << 16);
        G4[selfoff] = o;
    }
}

// ---------------- GEMM2b (MFMA): T[nrows x 64] = G1 * W2, bf16 out, NO bias ----------------

__global__ __launch_bounds__(256) void gemm2b_mfma(const unsigned short* __restrict__ X,
                                                   const unsigned short* __restrict__ WB2,
                                                   unsigned short* __restrict__ T, int nrows) {
    __shared__ __align__(16) unsigned short Xs[128 * 136];
    __shared__ __align__(16) unsigned short Cs[128 * 68];
    const int t = threadIdx.x;
    const int r0 = blockIdx.x * 128;

    const uint4* Xg = (const uint4*)X;
    #pragma unroll
    for (int i = 0; i < 8; ++i) {
        int idx = t + 256 * i;
        int row = idx >> 4, c8 = idx & 15;
        uint4 v = {0u, 0u, 0u, 0u};
        if (r0 + row < nrows) v = Xg[(size_t)(r0 + row) * 16 + c8];
        *reinterpret_cast<uint4*>(&Xs[row * 136 + c8 * 8]) = v;
    }
    __syncthreads();

    const int lane = t & 63, w = t >> 6;
    const int m0 = w * 32;
    short8 a[2][4];
    #pragma unroll
    for (int rt = 0; rt < 2; ++rt)
        #pragma unroll
        for (int kk = 0; kk < 4; ++kk)
            a[rt][kk] = *reinterpret_cast<const short8*>(
                &Xs[(m0 + rt * 16 + (lane & 15)) * 136 + kk * 32 + (lane >> 4) * 8]);

    short8 b[4][4];
    #pragma unroll
    for (int n = 0; n < 4; ++n)
        #pragma unroll
        for (int kk = 0; kk < 4; ++kk)
            b[n][kk] = *reinterpret_cast<const short8*>(
                WB2 + (size_t)((n * 4 + kk) * 64 + lane) * 8);

    f32x4 acc[2][4];
    #pragma unroll
    for (int rt = 0; rt < 2; ++rt)
        #pragma unroll
        for (int n = 0; n < 4; ++n) {
            acc[rt][n] = (f32x4){0.f, 0.f, 0.f, 0.f};
            #pragma unroll
            for (int kk = 0; kk < 4; ++kk)
                acc[rt][n] = __builtin_amdgcn_mfma_f32_16x16x32_bf16(
                    a[rt][kk], b[n][kk], acc[rt][n], 0, 0, 0);
        }

    __syncthreads();
    #pragma unroll
    for (int rt = 0; rt < 2; ++rt)
        #pragma unroll
        for (int n = 0; n < 4; ++n)
            #pragma unroll
            for (int r = 0; r < 4; ++r) {
                int row = m0 + rt * 16 + (lane >> 4) * 4 + r;
                Cs[row * 68 + n * 16 + (lane & 15)] = f2bf_raw(acc[rt][n][r]);
            }
    __syncthreads();
    #pragma unroll
    for (int i = 0; i < 8; ++i) {
        int idx = t + 256 * i;
        int row = idx >> 4, c4 = idx & 15;
        if (r0 + row < nrows) {
            uint2 v = *reinterpret_cast<const uint2*>(&Cs[row * 68 + c4 * 4]);
            *reinterpret_cast<uint2*>(T + (size_t)(r0 + row) * 64 + c4 * 4) = v;
        }
    }
}

// ---------------- Aggregation 2 + bias + log_softmax (64 ch, row-major T), di-factored ----------

__global__ __launch_bounds__(128) void agg64_final(const uint4* __restrict__ T4,
                                                   const uint2* __restrict__ nmeta,
                                                   const uint2* __restrict__ epack,
                                                   const float* __restrict__ b2f,
                                                   void* __restrict__ OUTv, int n,
                                                   const int* __restrict__ flag) {
    const int lane = threadIdx.x & 63;
    const int g = lane >> 3;
    const int sub = lane & 7;
    const int node = blockIdx.x * 2 + (threadIdx.x >> 6);
    if (node >= n) return;
    const int outf32 = *flag;

    const unsigned selfoff = ((unsigned)node << 3) + (unsigned)sub;
    uint4 vself = T4[selfoff];

    const uint2 meta = nmeta[node];
    const int base = (int)meta.x;
    const int cnt = (int)meta.y;
    const int end = base + cnt;
    const float di = rsqrtf((float)(cnt + 1));

    f32x2 acc[4];
    {
        const float ws = (g == 0) ? di : 0.f;   // di-factored
        acc[0] = (f32x2){ws * lo_f(vself.x), ws * hi_f(vself.x)};
        acc[1] = (f32x2){ws * lo_f(vself.y), ws * hi_f(vself.y)};
        acc[2] = (f32x2){ws * lo_f(vself.z), ws * hi_f(vself.z)};
        acc[3] = (f32x2){ws * lo_f(vself.w), ws * hi_f(vself.w)};
    }

    int j = base;
    for (; j + 15 < end; j += 16) {          // 16 edges, 2 gathers per lane in flight
        uint2 e0 = epack[j + g];
        uint2 e1 = epack[j + 8 + g];
        uint4 v0 = T4[(e0.x << 3) + (unsigned)sub];
        uint4 v1 = T4[(e1.x << 3) + (unsigned)sub];
        acc8v(acc, v0, epw_f(e0));
        acc8v(acc, v1, epw_f(e1));
    }
    for (; j + 7 < end; j += 8) {            // 8 edges
        uint2 e0 = epack[j + g];
        uint4 v0 = T4[(e0.x << 3) + (unsigned)sub];
        acc8v(acc, v0, epw_f(e0));
    }
    if (j + g < end) {                       // tail (<8 edges), group-predicated
        uint2 e0 = epack[j + g];
        uint4 v0 = T4[(e0.x << 3) + (unsigned)sub];
        acc8v(acc, v0, epw_f(e0));
    }

    float a8[8];
    #pragma unroll
    for (int i = 0; i < 4; ++i) { a8[2 * i] = acc[i].x; a8[2 * i + 1] = acc[i].y; }
    #pragma unroll
    for (int i = 0; i < 8; ++i) {            // combine the 8 edge-groups
        a8[i] += __shfl_xor(a8[i], 8, 64);
        a8[i] += __shfl_xor(a8[i], 16, 64);
        a8[i] += __shfl_xor(a8[i], 32, 64);
    }

    if (g == 0) {                            // lanes 0..7 hold the full 64-ch row
        const float4* b4 = (const float4*)b2f;
        float4 blo = b4[sub * 2], bhi = b4[sub * 2 + 1];
        a8[0] = fmaf(di, a8[0], blo.x);
        a8[1] = fmaf(di, a8[1], blo.y);
        a8[2] = fmaf(di, a8[2], blo.z);
        a8[3] = fmaf(di, a8[3], blo.w);
        a8[4] = fmaf(di, a8[4], bhi.x);
        a8[5] = fmaf(di, a8[5], bhi.y);
        a8[6] = fmaf(di, a8[6], bhi.z);
        a8[7] = fmaf(di, a8[7], bhi.w);

        float m = fmaxf(fmaxf(fmaxf(a8[0], a8[1]), fmaxf(a8[2], a8[3])),
                        fmaxf(fmaxf(a8[4], a8[5]), fmaxf(a8[6], a8[7])));
        m = fmaxf(m, __shfl_xor(m, 1, 64));
        m = fmaxf(m, __shfl_xor(m, 2, 64));
        m = fmaxf(m, __shfl_xor(m, 4, 64));
        float s = __expf(a8[0] - m) + __expf(a8[1] - m) + __expf(a8[2] - m) + __expf(a8[3] - m) +
                  __expf(a8[4] - m) + __expf(a8[5] - m) + __expf(a8[6] - m) + __expf(a8[7] - m);
        s += __shfl_xor(s, 1, 64);
        s += __shfl_xor(s, 2, 64);
        s += __shfl_xor(s, 4, 64);
        const float lse = m + __logf(s);

        if (outf32) {
            float4* Of = (float4*)OUTv;
            float4 o0 = {a8[0] - lse, a8[1] - lse, a8[2] - lse, a8[3] - lse};
            float4 o1 = {a8[4] - lse, a8[5] - lse, a8[6] - lse, a8[7] - lse};
            Of[(size_t)node * 16 + sub * 2] = o0;
            Of[(size_t)node * 16 + sub * 2 + 1] = o1;
        } else {
            uint4 o;
            o.x = (unsigned)f2bf_raw(a8[0] - lse) | ((unsigned)f2bf_raw(a8[1] - lse) << 16);
            o.y = (unsigned)f2bf_raw(a8[2] - lse) | ((unsigned)f2bf_raw(a8[3] - lse) << 16);
            o.z = (unsigned)f2bf_raw(a8[4] - lse) | ((unsigned)f2bf_raw(a8[5] - lse) << 16);
            o.w = (unsigned)f2bf_raw(a8[6] - lse) | ((unsigned)f2bf_raw(a8[7] - lse) << 16);
            ((uint4*)OUTv)[(size_t)node * 8 + sub] = o;
        }
    }
}

// ---------------- launch ----------------

extern "C" void kernel_launch(void* const* d_in, const int* in_sizes, int n_in,
                              void* d_out, int out_size, void* d_ws, size_t ws_size,
                              hipStream_t stream) {
    const void* x  = d_in[0];
    const int*  ei = (const int*)d_in[1];
    const void* W1 = d_in[2];
    const void* b1 = d_in[3];
    const void* W2 = d_in[4];
    const void* b2 = d_in[5];

    const int N = in_sizes[0] / 128;
    const int E = in_sizes[1] / 2;
    const int* src = ei;
    const int* dst = ei + E;
    const int NBUK = (N + NPB - 1) / NPB;     // 391 for N=100K

    char* p = (char*)d_ws;
    auto alloc = [&](size_t bytes) { char* q = p; p += (bytes + 255) & ~255ull; return q; };
    int*   flag   = (int*)  alloc(4);
    uint2* nmeta  = (uint2*)alloc((size_t)N * 8);
    float* dinv   = (float*)alloc((size_t)N * 4);
    int*   bktcnt = (int*)  alloc((size_t)NBUK * 4);
    int*   bofs   = (int*)  alloc((size_t)(NBUK + 1) * 4);
    int*   bcur   = (int*)  alloc((size_t)NBUK * 4);
    float* b1f    = (float*)alloc(128 * 4);
    float* b2f    = (float*)alloc(64 * 4);
    unsigned short* WB1 = (unsigned short*)alloc(16384 * 2);
    unsigned short* WB2 = (unsigned short*)alloc(8192 * 2);
    unsigned* big = (unsigned*)alloc((size_t)N * 128 * 2);   // H row-major (25.6 MB), later T (12.8 MB)
    unsigned* packed = (unsigned*)d_out;          // 6.4 MB scratch in d_out (dead after csr_fine2)
    uint2*    epack  = (uint2*)d_in[1];           // {src, w_bits}; overwrites src+dst (dead after ms_scatter)
    unsigned* g1 = (unsigned*)d_in[0];            // G1 row-major into x's buffer (x dead after gemm1)
    unsigned short* T = (unsigned short*)big;     // T (row-major) overwrites H (dead after agg1)
    (void)ws_size; (void)n_in; (void)out_size;

    // prep covers: weights 24576 + biases 192 + bktcnt NBUK -> 99 blocks is enough for N<=262144? 
    // need 24768 + NBUK threads; NBUK<=1024 -> 25792 <= 101*256
    const int PREPB = (24768 + NBUK + 255) / 256;
    prep_kernel<<<PREPB, 256, 0, stream>>>((const unsigned short*)W1, W1, W2, b1, b2,
                                           WB1, WB2, b1f, b2f, flag, bktcnt,
                                           in_sizes[2], NBUK);
    const int MSB = (E + 4095) / 4096;
    ms_count_kernel<<<MSB, 256, 0, stream>>>(dst, bktcnt, E, NBUK);
    bscan_kernel<<<1, 1024, 0, stream>>>(bktcnt, bofs, bcur, NBUK, E);
    ms_scatter_kernel<<<MSB, 256, 0, stream>>>(src, dst, bcur, packed, E, NBUK);
    csr_fine2_kernel<<<NBUK, 256, 0, stream>>>(packed, bofs, nmeta, dinv, (unsigned*)epack, N);
    epw_kernel<<<(E + 255) / 256, 256, 0, stream>>>((unsigned*)epack, dinv, E);

    const int GB = (N + 127) / 128;
    gemm1_mfma<<<GB, 256, 0, stream>>>(x, WB1, (unsigned short*)big, N, flag);
    agg128_v7<<<(N + 1) / 2, 128, 0, stream>>>((const uint4*)big, nmeta, epack, b1f, (uint4*)g1, N);
    gemm2b_mfma<<<GB, 256, 0, stream>>>((const unsigned short*)g1, WB2, T, N);
    agg64_final<<<(N + 1) / 2, 128, 0, stream>>>((const uint4*)T, nmeta, epack, b2f, d_out, N, flag);
}

// Round 9
// 304.408 us; speedup vs baseline: 1.6035x; 1.0280x over previous
//
#include <hip/hip_runtime.h>
#include <hip/hip_bf16.h>

typedef __hip_bfloat16 bf16;
typedef short short8 __attribute__((ext_vector_type(8)));
typedef float f32x4 __attribute__((ext_vector_type(4)));
typedef float f32x2 __attribute__((ext_vector_type(2)));

#define NPB 256          // nodes per bucket (coarse radix = dst>>8)
#define MAXBUK 1024      // supports N <= 262144

__device__ __forceinline__ float bf2f_raw(unsigned short u) {
    unsigned x = ((unsigned)u) << 16; float f; __builtin_memcpy(&f, &x, 4); return f;
}
__device__ __forceinline__ unsigned short f2bf_raw(float f) {   // RNE
    unsigned u; __builtin_memcpy(&u, &f, 4);
    u += 0x7FFFu + ((u >> 16) & 1u);
    return (unsigned short)(u >> 16);
}
__device__ __forceinline__ float lo_f(unsigned u) {
    unsigned x = u << 16; float f; __builtin_memcpy(&f, &x, 4); return f;
}
__device__ __forceinline__ float hi_f(unsigned u) {
    unsigned x = u & 0xffff0000u; float f; __builtin_memcpy(&f, &x, 4); return f;
}

// ---------------- prep (fused sniff + weight repack + bias conv + bktcnt zero) ----------------

__global__ __launch_bounds__(256) void prep_kernel(const unsigned short* __restrict__ W1s,
                                                   const void* __restrict__ W1p,
                                                   const void* __restrict__ W2p,
                                                   const void* __restrict__ b1p,
                                                   const void* __restrict__ b2p,
                                                   unsigned short* __restrict__ WB1,
                                                   unsigned short* __restrict__ WB2,
                                                   float* __restrict__ b1f,
                                                   float* __restrict__ b2f,
                                                   int* __restrict__ flag,
                                                   int* __restrict__ bktcnt,
                                                   int nshorts, int nbuk) {
    __shared__ int red[256];
    const int tt = threadIdx.x;
    const int sample = min(nshorts, 2048);
    int c = 0;
    for (int i = tt; i < sample; i += 256) {
        unsigned e = (W1s[i] >> 7) & 0xFFu;
        if (e >= 140u || (e >= 1u && e <= 40u)) c++;
    }
    red[tt] = c;
    __syncthreads();
    for (int o = 128; o > 0; o >>= 1) {
        if (tt < o) red[tt] += red[tt + o];
        __syncthreads();
    }
    const int isf32 = (red[0] > sample / 8) ? 1 : 0;
    if (blockIdx.x == 0 && tt == 0) *flag = isf32;

    const int t = blockIdx.x * 256 + tt;
    const int T1 = 16384, T2 = 8192;
    if (t < T1) {
        int j = t & 7, l = (t >> 3) & 63, f = t >> 9;
        int n = f >> 2, kk = f & 3;
        int k = kk * 32 + (l >> 4) * 8 + j;
        int col = n * 16 + (l & 15);
        WB1[t] = isf32 ? f2bf_raw(((const float*)W1p)[k * 128 + col])
                       : ((const unsigned short*)W1p)[k * 128 + col];
    } else if (t < T1 + T2) {
        int o = t - T1;
        int j = o & 7, l = (o >> 3) & 63, f = o >> 9;
        int n = f >> 2, kk = f & 3;
        int k = kk * 32 + (l >> 4) * 8 + j;
        int col = n * 16 + (l & 15);
        WB2[o] = isf32 ? f2bf_raw(((const float*)W2p)[k * 64 + col])
                       : ((const unsigned short*)W2p)[k * 64 + col];
    } else if (t < T1 + T2 + 128) {
        int o = t - T1 - T2;
        b1f[o] = isf32 ? ((const float*)b1p)[o] : bf2f_raw(((const unsigned short*)b1p)[o]);
    } else if (t < T1 + T2 + 192) {
        int o = t - T1 - T2 - 128;
        b2f[o] = isf32 ? ((const float*)b2p)[o] : bf2f_raw(((const unsigned short*)b2p)[o]);
    } else if (t < T1 + T2 + 192 + nbuk) {
        bktcnt[t - T1 - T2 - 192] = 0;
    }
}

// ---------------- CSR build, bucket-granular ----------------

__global__ __launch_bounds__(256) void ms_count_kernel(const int* __restrict__ dst,
                                                       int* __restrict__ bktcnt,
                                                       int E, int nbuk) {
    __shared__ int cnt[MAXBUK];
    const int t = threadIdx.x;
    const int e0 = blockIdx.x * 4096;
    const int e1 = min(E, e0 + 4096);
    for (int b = t; b < nbuk; b += 256) cnt[b] = 0;
    __syncthreads();
    for (int e = e0 + t; e < e1; e += 256) atomicAdd(&cnt[dst[e] >> 8], 1);
    __syncthreads();
    for (int b = t; b < nbuk; b += 256) {
        int c = cnt[b];
        if (c) atomicAdd(&bktcnt[b], c);
    }
}

__global__ __launch_bounds__(1024) void bscan_kernel(const int* __restrict__ bktcnt,
                                                     int* __restrict__ bofs,
                                                     int* __restrict__ bcur,
                                                     int nbuk, int total) {
    __shared__ int ps[1024];
    const int t = threadIdx.x;
    int v = (t < nbuk) ? bktcnt[t] : 0;
    ps[t] = v;
    __syncthreads();
    for (int o = 1; o < 1024; o <<= 1) {
        int u = (t >= o) ? ps[t - o] : 0;
        __syncthreads();
        ps[t] += u;
        __syncthreads();
    }
    if (t < nbuk) {
        int ex = ps[t] - v;
        bofs[t] = ex;
        bcur[t] = ex;
    }
    if (t == 0) bofs[nbuk] = total;
}

__global__ __launch_bounds__(256) void ms_scatter_kernel(const int* __restrict__ src,
                                                         const int* __restrict__ dst,
                                                         int* __restrict__ bcur,
                                                         unsigned* __restrict__ packed,
                                                         int E, int nbuk) {
    __shared__ int cnt[MAXBUK];
    __shared__ int gbase[MAXBUK];
    const int t = threadIdx.x;
    const int e0 = blockIdx.x * 4096;
    const int e1 = min(E, e0 + 4096);
    for (int b = t; b < nbuk; b += 256) cnt[b] = 0;
    __syncthreads();
    for (int e = e0 + t; e < e1; e += 256) atomicAdd(&cnt[dst[e] >> 8], 1);
    __syncthreads();
    for (int b = t; b < nbuk; b += 256) {
        int c = cnt[b];
        gbase[b] = c ? atomicAdd(&bcur[b], c) : 0;
        cnt[b] = 0;
    }
    __syncthreads();
    for (int e = e0 + t; e < e1; e += 256) {
        int d = dst[e];
        int b = d >> 8;
        int r = atomicAdd(&cnt[b], 1);
        packed[gbase[b] + r] = ((unsigned)(d & 255) << 24) | (unsigned)src[e];
    }
}

// 4) csr_fine2: per-node nmeta {base,deg} + dinv; place edge src ids into epack[pos].x.
__global__ __launch_bounds__(256) void csr_fine2_kernel(const unsigned* __restrict__ packed,
                                                        const int* __restrict__ bofs,
                                                        uint2* __restrict__ nmeta,
                                                        float* __restrict__ dinv,
                                                        unsigned* __restrict__ epu, int n) {
    __shared__ int cnt2[NPB];
    __shared__ int cur[NPB];
    const int t = threadIdx.x;
    const int b = blockIdx.x;
    const int node0 = b << 8;
    const int nn = min(NPB, n - node0);
    cnt2[t] = 0;
    __syncthreads();
    const int beg = bofs[b], end = bofs[b + 1];
    for (int i = beg + t; i < end; i += 256) atomicAdd(&cnt2[packed[i] >> 24], 1);
    __syncthreads();
    int c = cnt2[t];
    cur[t] = c;
    __syncthreads();
    for (int o = 1; o < 256; o <<= 1) {        // inclusive scan over 256 local counts
        int u = (t >= o) ? cur[t - o] : 0;
        __syncthreads();
        cur[t] += u;
        __syncthreads();
    }
    const int base = beg + cur[t] - c;          // exclusive
    if (t < nn) {
        nmeta[node0 + t] = make_uint2((unsigned)base, (unsigned)c);
        dinv[node0 + t] = rsqrtf((float)(c + 1));
    }
    __syncthreads();
    cur[t] = base;
    __syncthreads();
    for (int i = beg + t; i < end; i += 256) {
        unsigned u = packed[i];
        int pos = atomicAdd(&cur[u >> 24], 1);
        epu[2 * pos] = u & 0xFFFFFFu;           // epack[pos].x = src
    }
}

// 5) epw: fill epack[j].y = bits(dinv[src_j]).
__global__ __launch_bounds__(256) void epw_kernel(unsigned* __restrict__ epu,
                                                  const float* __restrict__ dinv, int E) {
    int i = blockIdx.x * 256 + threadIdx.x;
    if (i < E) {
        unsigned s = epu[2 * i];
        float w = dinv[s];
        unsigned wb; __builtin_memcpy(&wb, &w, 4);
        epu[2 * i + 1] = wb;
    }
}

// ---------------- GEMM1 (MFMA): H[nrows x 128] = X * W1, FP8-E4M3 out (HW cvt) ----------------
// H row = 128 bytes = 2 cache lines -> halves agg1's line-fill count (the measured limiter).

__global__ __launch_bounds__(256) void gemm1_mfma(const void* __restrict__ Xp,
                                                  const unsigned short* __restrict__ WB1,
                                                  unsigned char* __restrict__ Hf8, int nrows,
                                                  const int* __restrict__ flag) {
    __shared__ __align__(16) unsigned short Xs[128 * 136];
    __shared__ __align__(16) unsigned short Cs[128 * 68];
    const int t = threadIdx.x;
    const int r0 = blockIdx.x * 128;
    const int isf32 = *flag;

    if (isf32) {
        const float4* Xg = (const float4*)Xp;
        #pragma unroll
        for (int i = 0; i < 16; ++i) {
            int idx = t + 256 * i;
            int row = idx >> 5, c4 = idx & 31;
            float4 v = {0.f, 0.f, 0.f, 0.f};
            if (r0 + row < nrows) v = Xg[(size_t)(r0 + row) * 32 + c4];
            unsigned lo = (unsigned)f2bf_raw(v.x) | ((unsigned)f2bf_raw(v.y) << 16);
            unsigned hi = (unsigned)f2bf_raw(v.z) | ((unsigned)f2bf_raw(v.w) << 16);
            *reinterpret_cast<uint2*>(&Xs[row * 136 + c4 * 4]) = make_uint2(lo, hi);
        }
    } else {
        const uint4* Xg = (const uint4*)Xp;
        #pragma unroll
        for (int i = 0; i < 8; ++i) {
            int idx = t + 256 * i;
            int row = idx >> 4, c8 = idx & 15;
            uint4 v = {0u, 0u, 0u, 0u};
            if (r0 + row < nrows) v = Xg[(size_t)(r0 + row) * 16 + c8];
            *reinterpret_cast<uint4*>(&Xs[row * 136 + c8 * 8]) = v;
        }
    }
    __syncthreads();

    const int lane = t & 63, w = t >> 6;
    const int m0 = w * 32;
    short8 a[2][4];
    #pragma unroll
    for (int rt = 0; rt < 2; ++rt)
        #pragma unroll
        for (int kk = 0; kk < 4; ++kk)
            a[rt][kk] = *reinterpret_cast<const short8*>(
                &Xs[(m0 + rt * 16 + (lane & 15)) * 136 + kk * 32 + (lane >> 4) * 8]);

    for (int p = 0; p < 2; ++p) {
        short8 b[4][4];
        #pragma unroll
        for (int n = 0; n < 4; ++n)
            #pragma unroll
            for (int kk = 0; kk < 4; ++kk)
                b[n][kk] = *reinterpret_cast<const short8*>(
                    WB1 + (size_t)(((p * 4 + n) * 4 + kk) * 64 + lane) * 8);
        f32x4 acc[2][4];
        #pragma unroll
        for (int rt = 0; rt < 2; ++rt)
            #pragma unroll
            for (int n = 0; n < 4; ++n) {
                acc[rt][n] = (f32x4){0.f, 0.f, 0.f, 0.f};
                #pragma unroll
                for (int kk = 0; kk < 4; ++kk)
                    acc[rt][n] = __builtin_amdgcn_mfma_f32_16x16x32_bf16(
                        a[rt][kk], b[n][kk], acc[rt][n], 0, 0, 0);
            }
        if (p) __syncthreads();
        #pragma unroll
        for (int rt = 0; rt < 2; ++rt)
            #pragma unroll
            for (int n = 0; n < 4; ++n)
                #pragma unroll
                for (int r = 0; r < 4; ++r) {
                    int row = m0 + rt * 16 + (lane >> 4) * 4 + r;
                    Cs[row * 68 + n * 16 + (lane & 15)] = f2bf_raw(acc[rt][n][r]);
                }
        __syncthreads();
        // fp8 epilogue: 128 rows x 8 chunks(8ch) = 1024 units -> 4 iters
        #pragma unroll
        for (int i = 0; i < 4; ++i) {
            int idx = t + 256 * i;
            int row = idx >> 3, c8 = idx & 7;
            if (r0 + row < nrows) {
                uint2 va = *reinterpret_cast<const uint2*>(&Cs[row * 68 + c8 * 8]);
                uint2 vb = *reinterpret_cast<const uint2*>(&Cs[row * 68 + c8 * 8 + 4]);
                int w0 = __builtin_amdgcn_cvt_pk_fp8_f32(lo_f(va.x), hi_f(va.x), 0, false);
                w0 = __builtin_amdgcn_cvt_pk_fp8_f32(lo_f(va.y), hi_f(va.y), w0, true);
                int w1 = __builtin_amdgcn_cvt_pk_fp8_f32(lo_f(vb.x), hi_f(vb.x), 0, false);
                w1 = __builtin_amdgcn_cvt_pk_fp8_f32(lo_f(vb.y), hi_f(vb.y), w1, true);
                *reinterpret_cast<uint2*>(Hf8 + (size_t)(r0 + row) * 128 + p * 64 + c8 * 8) =
                    make_uint2((unsigned)w0, (unsigned)w1);
            }
        }
        if (!p) __syncthreads();
    }
}

// ---------------- Aggregation v8 (layer 1): fp8 gather, 8 groups x 8 subs, bf16 out ----------------
// Row = 128B fp8: one dwordx4 gather covers 8 rows/wave (half the instructions AND half the
// line-fills of the bf16 version). Decode via HW v_cvt_pk_f32_fp8; f32 accumulate; G1 bf16.

__device__ __forceinline__ float epw_f(uint2 e) {
    float w; __builtin_memcpy(&w, &e.y, 4); return w;
}

__device__ __forceinline__ void accf8(f32x2* acc, uint4 v, float w) {
    f32x2 wv = {w, w};
    acc[0] += __builtin_amdgcn_cvt_pk_f32_fp8(v.x, false) * wv;
    acc[1] += __builtin_amdgcn_cvt_pk_f32_fp8(v.x, true)  * wv;
    acc[2] += __builtin_amdgcn_cvt_pk_f32_fp8(v.y, false) * wv;
    acc[3] += __builtin_amdgcn_cvt_pk_f32_fp8(v.y, true)  * wv;
    acc[4] += __builtin_amdgcn_cvt_pk_f32_fp8(v.z, false) * wv;
    acc[5] += __builtin_amdgcn_cvt_pk_f32_fp8(v.z, true)  * wv;
    acc[6] += __builtin_amdgcn_cvt_pk_f32_fp8(v.w, false) * wv;
    acc[7] += __builtin_amdgcn_cvt_pk_f32_fp8(v.w, true)  * wv;
}

__global__ __launch_bounds__(128) void agg128_v8(const uint4* __restrict__ H8,
                                                 const uint2* __restrict__ nmeta,
                                                 const uint2* __restrict__ epack,
                                                 const float* __restrict__ biasf,
                                                 uint4* __restrict__ G4, int n) {
    const int lane = threadIdx.x & 63;
    const int g = lane >> 3;          // 8 edge groups
    const int sub = lane & 7;         // 16B chunk of the 128B fp8 row (16 channels)
    const int node = blockIdx.x * 2 + (threadIdx.x >> 6);
    if (node >= n) return;

    uint4 vself = H8[((unsigned)node << 3) + (unsigned)sub];

    const uint2 meta = nmeta[node];
    const int base = (int)meta.x;
    const int cnt = (int)meta.y;
    const int end = base + cnt;
    const float di = rsqrtf((float)(cnt + 1));

    f32x2 acc[8];
    #pragma unroll
    for (int i = 0; i < 8; ++i) acc[i] = (f32x2){0.f, 0.f};
    accf8(acc, vself, (g == 0) ? di : 0.f);    // di-factored self term

    int j = base;
    for (; j + 15 < end; j += 16) {            // 16 edges, 2 gathers/lane in flight
        uint2 e0 = epack[j + g];
        uint2 e1 = epack[j + 8 + g];
        uint4 v0 = H8[(e0.x << 3) + (unsigned)sub];
        uint4 v1 = H8[(e1.x << 3) + (unsigned)sub];
        accf8(acc, v0, epw_f(e0));
        accf8(acc, v1, epw_f(e1));
    }
    for (; j + 7 < end; j += 8) {              // 8 edges
        uint2 e0 = epack[j + g];
        uint4 v0 = H8[(e0.x << 3) + (unsigned)sub];
        accf8(acc, v0, epw_f(e0));
    }
    if (j + g < end) {                         // tail (<8 edges), group-predicated
        uint2 e0 = epack[j + g];
        uint4 v0 = H8[(e0.x << 3) + (unsigned)sub];
        accf8(acc, v0, epw_f(e0));
    }

    float af[16];
    #pragma unroll
    for (int i = 0; i < 8; ++i) { af[2 * i] = acc[i].x; af[2 * i + 1] = acc[i].y; }
    #pragma unroll
    for (int i = 0; i < 16; ++i) {             // combine the 8 edge-groups
        af[i] += __shfl_xor(af[i], 8, 64);
        af[i] += __shfl_xor(af[i], 16, 64);
        af[i] += __shfl_xor(af[i], 32, 64);
    }

    if (g == 0) {                              // lanes 0..7: channels [sub*16, sub*16+16)
        const float4* b4 = (const float4*)biasf;
        unsigned ow[8];
        #pragma unroll
        for (int q = 0; q < 4; ++q) {
            float4 bb = b4[sub * 4 + q];
            float o0 = fmaxf(fmaf(di, af[4 * q + 0], bb.x), 0.f);
            float o1 = fmaxf(fmaf(di, af[4 * q + 1], bb.y), 0.f);
            float o2 = fmaxf(fmaf(di, af[4 * q + 2], bb.z), 0.f);
            float o3 = fmaxf(fmaf(di, af[4 * q + 3], bb.w), 0.f);
            ow[2 * q] = (unsigned)f2bf_raw(o0) | ((unsigned)f2bf_raw(o1) << 16);
            ow[2 * q + 1] = (unsigned)f2bf_raw(o2) | ((unsigned)f2bf_raw(o3) << 16);
        }
        uint4 oa = {ow[0], ow[1], ow[2], ow[3]};
        uint4 ob = {ow[4], ow[5], ow[6], ow[7]};
        G4[((unsigned)node << 4) + (unsigned)sub * 2] = oa;
        G4[((unsigned)node << 4) + (unsigned)sub * 2 + 1] = ob;
    }
}

// ---------------- GEMM2b (MFMA): T[nrows x 64] = G1 * W2, bf16 out, NO bias ----------------

__global__ __launch_bounds__(256) void gemm2b_mfma(const unsigned short* __restrict__ X,
                                                   const unsigned short* __restrict__ WB2,
                                                   unsigned short* __restrict__ T, int nrows) {
    __shared__ __align__(16) unsigned short Xs[128 * 136];
    __shared__ __align__(16) unsigned short Cs[128 * 68];
    const int t = threadIdx.x;
    const int r0 = blockIdx.x * 128;

    const uint4* Xg = (const uint4*)X;
    #pragma unroll
    for (int i = 0; i < 8; ++i) {
        int idx = t + 256 * i;
        int row = idx >> 4, c8 = idx & 15;
        uint4 v = {0u, 0u, 0u, 0u};
        if (r0 + row < nrows) v = Xg[(size_t)(r0 + row) * 16 + c8];
        *reinterpret_cast<uint4*>(&Xs[row * 136 + c8 * 8]) = v;
    }
    __syncthreads();

    const int lane = t & 63, w = t >> 6;
    const int m0 = w * 32;
    short8 a[2][4];
    #pragma unroll
    for (int rt = 0; rt < 2; ++rt)
        #pragma unroll
        for (int kk = 0; kk < 4; ++kk)
            a[rt][kk] = *reinterpret_cast<const short8*>(
                &Xs[(m0 + rt * 16 + (lane & 15)) * 136 + kk * 32 + (lane >> 4) * 8]);

    short8 b[4][4];
    #pragma unroll
    for (int n = 0; n < 4; ++n)
        #pragma unroll
        for (int kk = 0; kk < 4; ++kk)
            b[n][kk] = *reinterpret_cast<const short8*>(
                WB2 + (size_t)((n * 4 + kk) * 64 + lane) * 8);

    f32x4 acc[2][4];
    #pragma unroll
    for (int rt = 0; rt < 2; ++rt)
        #pragma unroll
        for (int n = 0; n < 4; ++n) {
            acc[rt][n] = (f32x4){0.f, 0.f, 0.f, 0.f};
            #pragma unroll
            for (int kk = 0; kk < 4; ++kk)
                acc[rt][n] = __builtin_amdgcn_mfma_f32_16x16x32_bf16(
                    a[rt][kk], b[n][kk], acc[rt][n], 0, 0, 0);
        }

    __syncthreads();
    #pragma unroll
    for (int rt = 0; rt < 2; ++rt)
        #pragma unroll
        for (int n = 0; n < 4; ++n)
            #pragma unroll
            for (int r = 0; r < 4; ++r) {
                int row = m0 + rt * 16 + (lane >> 4) * 4 + r;
                Cs[row * 68 + n * 16 + (lane & 15)] = f2bf_raw(acc[rt][n][r]);
            }
    __syncthreads();
    #pragma unroll
    for (int i = 0; i < 8; ++i) {
        int idx = t + 256 * i;
        int row = idx >> 4, c4 = idx & 15;
        if (r0 + row < nrows) {
            uint2 v = *reinterpret_cast<const uint2*>(&Cs[row * 68 + c4 * 4]);
            *reinterpret_cast<uint2*>(T + (size_t)(r0 + row) * 64 + c4 * 4) = v;
        }
    }
}

// ---------------- Aggregation 2 + bias + log_softmax (64 ch, row-major bf16 T) ----------------

__device__ __forceinline__ void acc8v(f32x2* acc, uint4 v, float w) {
    f32x2 wv = {w, w};
    acc[0] += (f32x2){lo_f(v.x), hi_f(v.x)} * wv;
    acc[1] += (f32x2){lo_f(v.y), hi_f(v.y)} * wv;
    acc[2] += (f32x2){lo_f(v.z), hi_f(v.z)} * wv;
    acc[3] += (f32x2){lo_f(v.w), hi_f(v.w)} * wv;
}

__global__ __launch_bounds__(128) void agg64_final(const uint4* __restrict__ T4,
                                                   const uint2* __restrict__ nmeta,
                                                   const uint2* __restrict__ epack,
                                                   const float* __restrict__ b2f,
                                                   void* __restrict__ OUTv, int n,
                                                   const int* __restrict__ flag) {
    const int lane = threadIdx.x & 63;
    const int g = lane >> 3;
    const int sub = lane & 7;
    const int node = blockIdx.x * 2 + (threadIdx.x >> 6);
    if (node >= n) return;
    const int outf32 = *flag;

    const unsigned selfoff = ((unsigned)node << 3) + (unsigned)sub;
    uint4 vself = T4[selfoff];

    const uint2 meta = nmeta[node];
    const int base = (int)meta.x;
    const int cnt = (int)meta.y;
    const int end = base + cnt;
    const float di = rsqrtf((float)(cnt + 1));

    f32x2 acc[4];
    {
        const float ws = (g == 0) ? di : 0.f;   // di-factored
        acc[0] = (f32x2){ws * lo_f(vself.x), ws * hi_f(vself.x)};
        acc[1] = (f32x2){ws * lo_f(vself.y), ws * hi_f(vself.y)};
        acc[2] = (f32x2){ws * lo_f(vself.z), ws * hi_f(vself.z)};
        acc[3] = (f32x2){ws * lo_f(vself.w), ws * hi_f(vself.w)};
    }

    int j = base;
    for (; j + 15 < end; j += 16) {          // 16 edges, 2 gathers per lane in flight
        uint2 e0 = epack[j + g];
        uint2 e1 = epack[j + 8 + g];
        uint4 v0 = T4[(e0.x << 3) + (unsigned)sub];
        uint4 v1 = T4[(e1.x << 3) + (unsigned)sub];
        acc8v(acc, v0, epw_f(e0));
        acc8v(acc, v1, epw_f(e1));
    }
    for (; j + 7 < end; j += 8) {            // 8 edges
        uint2 e0 = epack[j + g];
        uint4 v0 = T4[(e0.x << 3) + (unsigned)sub];
        acc8v(acc, v0, epw_f(e0));
    }
    if (j + g < end) {                       // tail (<8 edges), group-predicated
        uint2 e0 = epack[j + g];
        uint4 v0 = T4[(e0.x << 3) + (unsigned)sub];
        acc8v(acc, v0, epw_f(e0));
    }

    float a8[8];
    #pragma unroll
    for (int i = 0; i < 4; ++i) { a8[2 * i] = acc[i].x; a8[2 * i + 1] = acc[i].y; }
    #pragma unroll
    for (int i = 0; i < 8; ++i) {            // combine the 8 edge-groups
        a8[i] += __shfl_xor(a8[i], 8, 64);
        a8[i] += __shfl_xor(a8[i], 16, 64);
        a8[i] += __shfl_xor(a8[i], 32, 64);
    }

    if (g == 0) {                            // lanes 0..7 hold the full 64-ch row
        const float4* b4 = (const float4*)b2f;
        float4 blo = b4[sub * 2], bhi = b4[sub * 2 + 1];
        a8[0] = fmaf(di, a8[0], blo.x);
        a8[1] = fmaf(di, a8[1], blo.y);
        a8[2] = fmaf(di, a8[2], blo.z);
        a8[3] = fmaf(di, a8[3], blo.w);
        a8[4] = fmaf(di, a8[4], bhi.x);
        a8[5] = fmaf(di, a8[5], bhi.y);
        a8[6] = fmaf(di, a8[6], bhi.z);
        a8[7] = fmaf(di, a8[7], bhi.w);

        float m = fmaxf(fmaxf(fmaxf(a8[0], a8[1]), fmaxf(a8[2], a8[3])),
                        fmaxf(fmaxf(a8[4], a8[5]), fmaxf(a8[6], a8[7])));
        m = fmaxf(m, __shfl_xor(m, 1, 64));
        m = fmaxf(m, __shfl_xor(m, 2, 64));
        m = fmaxf(m, __shfl_xor(m, 4, 64));
        float s = __expf(a8[0] - m) + __expf(a8[1] - m) + __expf(a8[2] - m) + __expf(a8[3] - m) +
                  __expf(a8[4] - m) + __expf(a8[5] - m) + __expf(a8[6] - m) + __expf(a8[7] - m);
        s += __shfl_xor(s, 1, 64);
        s += __shfl_xor(s, 2, 64);
        s += __shfl_xor(s, 4, 64);
        const float lse = m + __logf(s);

        if (outf32) {
            float4* Of = (float4*)OUTv;
            float4 o0 = {a8[0] - lse, a8[1] - lse, a8[2] - lse, a8[3] - lse};
            float4 o1 = {a8[4] - lse, a8[5] - lse, a8[6] - lse, a8[7] - lse};
            Of[(size_t)node * 16 + sub * 2] = o0;
            Of[(size_t)node * 16 + sub * 2 + 1] = o1;
        } else {
            uint4 o;
            o.x = (unsigned)f2bf_raw(a8[0] - lse) | ((unsigned)f2bf_raw(a8[1] - lse) << 16);
            o.y = (unsigned)f2bf_raw(a8[2] - lse) | ((unsigned)f2bf_raw(a8[3] - lse) << 16);
            o.z = (unsigned)f2bf_raw(a8[4] - lse) | ((unsigned)f2bf_raw(a8[5] - lse) << 16);
            o.w = (unsigned)f2bf_raw(a8[6] - lse) | ((unsigned)f2bf_raw(a8[7] - lse) << 16);
            ((uint4*)OUTv)[(size_t)node * 8 + sub] = o;
        }
    }
}

// ---------------- launch ----------------

extern "C" void kernel_launch(void* const* d_in, const int* in_sizes, int n_in,
                              void* d_out, int out_size, void* d_ws, size_t ws_size,
                              hipStream_t stream) {
    const void* x  = d_in[0];
    const int*  ei = (const int*)d_in[1];
    const void* W1 = d_in[2];
    const void* b1 = d_in[3];
    const void* W2 = d_in[4];
    const void* b2 = d_in[5];

    const int N = in_sizes[0] / 128;
    const int E = in_sizes[1] / 2;
    const int* src = ei;
    const int* dst = ei + E;
    const int NBUK = (N + NPB - 1) / NPB;     // 391 for N=100K

    char* p = (char*)d_ws;
    auto alloc = [&](size_t bytes) { char* q = p; p += (bytes + 255) & ~255ull; return q; };
    int*   flag   = (int*)  alloc(4);
    uint2* nmeta  = (uint2*)alloc((size_t)N * 8);
    float* dinv   = (float*)alloc((size_t)N * 4);
    int*   bktcnt = (int*)  alloc((size_t)NBUK * 4);
    int*   bofs   = (int*)  alloc((size_t)(NBUK + 1) * 4);
    int*   bcur   = (int*)  alloc((size_t)NBUK * 4);
    float* b1f    = (float*)alloc(128 * 4);
    float* b2f    = (float*)alloc(64 * 4);
    unsigned short* WB1 = (unsigned short*)alloc(16384 * 2);
    unsigned short* WB2 = (unsigned short*)alloc(8192 * 2);
    unsigned* big = (unsigned*)alloc((size_t)N * 128 * 2);   // H fp8 (12.8 MB), later T bf16 (12.8 MB)
    unsigned* packed = (unsigned*)d_out;          // 6.4 MB scratch in d_out (dead after csr_fine2)
    uint2*    epack  = (uint2*)d_in[1];           // {src, w_bits}; overwrites src+dst (dead after ms_scatter)
    unsigned* g1 = (unsigned*)d_in[0];            // G1 bf16 row-major into x's buffer (x dead after gemm1)
    unsigned short* T = (unsigned short*)big;     // T (row-major bf16) overwrites H fp8 (dead after agg1)
    (void)ws_size; (void)n_in; (void)out_size;

    const int PREPB = (24768 + NBUK + 255) / 256;
    prep_kernel<<<PREPB, 256, 0, stream>>>((const unsigned short*)W1, W1, W2, b1, b2,
                                           WB1, WB2, b1f, b2f, flag, bktcnt,
                                           in_sizes[2], NBUK);
    const int MSB = (E + 4095) / 4096;
    ms_count_kernel<<<MSB, 256, 0, stream>>>(dst, bktcnt, E, NBUK);
    bscan_kernel<<<1, 1024, 0, stream>>>(bktcnt, bofs, bcur, NBUK, E);
    ms_scatter_kernel<<<MSB, 256, 0, stream>>>(src, dst, bcur, packed, E, NBUK);
    csr_fine2_kernel<<<NBUK, 256, 0, stream>>>(packed, bofs, nmeta, dinv, (unsigned*)epack, N);
    epw_kernel<<<(E + 255) / 256, 256, 0, stream>>>((unsigned*)epack, dinv, E);

    const int GB = (N + 127) / 128;
    gemm1_mfma<<<GB, 256, 0, stream>>>(x, WB1, (unsigned char*)big, N, flag);
    agg128_v8<<<(N + 1) / 2, 128, 0, stream>>>((const uint4*)big, nmeta, epack, b1f, (uint4*)g1, N);
    gemm2b_mfma<<<GB, 256, 0, stream>>>((const unsigned short*)g1, WB2, T, N);
    agg64_final<<<(N + 1) / 2, 128, 0, stream>>>((const uint4*)T, nmeta, epack, b2f, d_out, N, flag);
}

// Round 10
// 299.274 us; speedup vs baseline: 1.6310x; 1.0172x over previous
//
#include <hip/hip_runtime.h>
#include <hip/hip_bf16.h>

typedef __hip_bfloat16 bf16;
typedef short short8 __attribute__((ext_vector_type(8)));
typedef float f32x4 __attribute__((ext_vector_type(4)));
typedef float f32x2 __attribute__((ext_vector_type(2)));

#define NPB 256          // nodes per bucket (coarse radix = dst>>8)
#define MAXBUK 1024      // supports N <= 262144

__device__ __forceinline__ float bf2f_raw(unsigned short u) {
    unsigned x = ((unsigned)u) << 16; float f; __builtin_memcpy(&f, &x, 4); return f;
}
__device__ __forceinline__ unsigned short f2bf_raw(float f) {   // RNE
    unsigned u; __builtin_memcpy(&u, &f, 4);
    u += 0x7FFFu + ((u >> 16) & 1u);
    return (unsigned short)(u >> 16);
}
__device__ __forceinline__ float lo_f(unsigned u) {
    unsigned x = u << 16; float f; __builtin_memcpy(&f, &x, 4); return f;
}
__device__ __forceinline__ float hi_f(unsigned u) {
    unsigned x = u & 0xffff0000u; float f; __builtin_memcpy(&f, &x, 4); return f;
}

// ---------------- fatA: prep role (sniff + weight repack + bias conv) || ms_count role ----------
// Roles are block-uniform; bktcnt is zeroed by a preceding memset so both roles are independent.

__global__ __launch_bounds__(256) void fatA_kernel(const unsigned short* __restrict__ W1s,
                                                   const void* __restrict__ W1p,
                                                   const void* __restrict__ W2p,
                                                   const void* __restrict__ b1p,
                                                   const void* __restrict__ b2p,
                                                   unsigned short* __restrict__ WB1,
                                                   unsigned short* __restrict__ WB2,
                                                   float* __restrict__ b1f,
                                                   float* __restrict__ b2f,
                                                   int* __restrict__ flag, int nshorts,
                                                   const int* __restrict__ dst,
                                                   int* __restrict__ bktcnt,
                                                   int E, int nbuk, int prepb) {
    __shared__ int smem[MAXBUK];
    const int tt = threadIdx.x;
    if ((int)blockIdx.x < prepb) {
        // ---- prep role: every block sniffs the same 2048-short sample -> identical verdict
        const int sample = min(nshorts, 2048);
        int c = 0;
        for (int i = tt; i < sample; i += 256) {
            unsigned e = (W1s[i] >> 7) & 0xFFu;
            if (e >= 140u || (e >= 1u && e <= 40u)) c++;
        }
        smem[tt] = c;
        __syncthreads();
        for (int o = 128; o > 0; o >>= 1) {
            if (tt < o) smem[tt] += smem[tt + o];
            __syncthreads();
        }
        const int isf32 = (smem[0] > sample / 8) ? 1 : 0;
        if (blockIdx.x == 0 && tt == 0) *flag = isf32;

        const int t = blockIdx.x * 256 + tt;
        const int T1 = 16384, T2 = 8192;
        if (t < T1) {
            int j = t & 7, l = (t >> 3) & 63, f = t >> 9;
            int n = f >> 2, kk = f & 3;
            int k = kk * 32 + (l >> 4) * 8 + j;
            int col = n * 16 + (l & 15);
            WB1[t] = isf32 ? f2bf_raw(((const float*)W1p)[k * 128 + col])
                           : ((const unsigned short*)W1p)[k * 128 + col];
        } else if (t < T1 + T2) {
            int o = t - T1;
            int j = o & 7, l = (o >> 3) & 63, f = o >> 9;
            int n = f >> 2, kk = f & 3;
            int k = kk * 32 + (l >> 4) * 8 + j;
            int col = n * 16 + (l & 15);
            WB2[o] = isf32 ? f2bf_raw(((const float*)W2p)[k * 64 + col])
                           : ((const unsigned short*)W2p)[k * 64 + col];
        } else if (t < T1 + T2 + 128) {
            int o = t - T1 - T2;
            b1f[o] = isf32 ? ((const float*)b1p)[o] : bf2f_raw(((const unsigned short*)b1p)[o]);
        } else if (t < T1 + T2 + 192) {
            int o = t - T1 - T2 - 128;
            b2f[o] = isf32 ? ((const float*)b2p)[o] : bf2f_raw(((const unsigned short*)b2p)[o]);
        }
    } else {
        // ---- ms_count role
        const int e0 = ((int)blockIdx.x - prepb) * 4096;
        const int e1 = min(E, e0 + 4096);
        for (int b = tt; b < nbuk; b += 256) smem[b] = 0;
        __syncthreads();
        for (int e = e0 + tt; e < e1; e += 256) atomicAdd(&smem[dst[e] >> 8], 1);
        __syncthreads();
        for (int b = tt; b < nbuk; b += 256) {
            int c = smem[b];
            if (c) atomicAdd(&bktcnt[b], c);
        }
    }
}

// 2) bscan: exclusive scan of bucket totals -> bofs/bcur.
__global__ __launch_bounds__(1024) void bscan_kernel(const int* __restrict__ bktcnt,
                                                     int* __restrict__ bofs,
                                                     int* __restrict__ bcur,
                                                     int nbuk, int total) {
    __shared__ int ps[1024];
    const int t = threadIdx.x;
    int v = (t < nbuk) ? bktcnt[t] : 0;
    ps[t] = v;
    __syncthreads();
    for (int o = 1; o < 1024; o <<= 1) {
        int u = (t >= o) ? ps[t - o] : 0;
        __syncthreads();
        ps[t] += u;
        __syncthreads();
    }
    if (t < nbuk) {
        int ex = ps[t] - v;
        bofs[t] = ex;
        bcur[t] = ex;
    }
    if (t == 0) bofs[nbuk] = total;
}

// ---------------- fatB: gemm1 (fp8-out) role || ms_scatter role (LDS unioned) ----------------

__global__ __launch_bounds__(256) void fatB_kernel(const void* __restrict__ Xp,
                                                   const unsigned short* __restrict__ WB1,
                                                   unsigned char* __restrict__ Hf8, int nrows,
                                                   const int* __restrict__ flag,
                                                   const int* __restrict__ src,
                                                   const int* __restrict__ dst,
                                                   int* __restrict__ bcur,
                                                   unsigned* __restrict__ packed,
                                                   int E, int nbuk, int gb) {
    __shared__ __align__(16) char smem[52224];   // union: gemm1 {Xs 34816 + Cs 17408} | scatter {cnt 4096 + gbase 4096}
    const int t = threadIdx.x;
    if ((int)blockIdx.x < gb) {
        // ---- gemm1 role: H[nrows x 128] = X * W1, FP8-E4M3 out (2 cache lines/row)
        unsigned short* Xs = (unsigned short*)smem;            // [128][136]
        unsigned short* Cs = (unsigned short*)(smem + 34816);  // [128][68]
        const int r0 = blockIdx.x * 128;
        const int isf32 = *flag;

        if (isf32) {
            const float4* Xg = (const float4*)Xp;
            #pragma unroll
            for (int i = 0; i < 16; ++i) {
                int idx = t + 256 * i;
                int row = idx >> 5, c4 = idx & 31;
                float4 v = {0.f, 0.f, 0.f, 0.f};
                if (r0 + row < nrows) v = Xg[(size_t)(r0 + row) * 32 + c4];
                unsigned lo = (unsigned)f2bf_raw(v.x) | ((unsigned)f2bf_raw(v.y) << 16);
                unsigned hi = (unsigned)f2bf_raw(v.z) | ((unsigned)f2bf_raw(v.w) << 16);
                *reinterpret_cast<uint2*>(&Xs[row * 136 + c4 * 4]) = make_uint2(lo, hi);
            }
        } else {
            const uint4* Xg = (const uint4*)Xp;
            #pragma unroll
            for (int i = 0; i < 8; ++i) {
                int idx = t + 256 * i;
                int row = idx >> 4, c8 = idx & 15;
                uint4 v = {0u, 0u, 0u, 0u};
                if (r0 + row < nrows) v = Xg[(size_t)(r0 + row) * 16 + c8];
                *reinterpret_cast<uint4*>(&Xs[row * 136 + c8 * 8]) = v;
            }
        }
        __syncthreads();

        const int lane = t & 63, w = t >> 6;
        const int m0 = w * 32;
        short8 a[2][4];
        #pragma unroll
        for (int rt = 0; rt < 2; ++rt)
            #pragma unroll
            for (int kk = 0; kk < 4; ++kk)
                a[rt][kk] = *reinterpret_cast<const short8*>(
                    &Xs[(m0 + rt * 16 + (lane & 15)) * 136 + kk * 32 + (lane >> 4) * 8]);

        for (int p = 0; p < 2; ++p) {
            short8 b[4][4];
            #pragma unroll
            for (int n = 0; n < 4; ++n)
                #pragma unroll
                for (int kk = 0; kk < 4; ++kk)
                    b[n][kk] = *reinterpret_cast<const short8*>(
                        WB1 + (size_t)(((p * 4 + n) * 4 + kk) * 64 + lane) * 8);
            f32x4 acc[2][4];
            #pragma unroll
            for (int rt = 0; rt < 2; ++rt)
                #pragma unroll
                for (int n = 0; n < 4; ++n) {
                    acc[rt][n] = (f32x4){0.f, 0.f, 0.f, 0.f};
                    #pragma unroll
                    for (int kk = 0; kk < 4; ++kk)
                        acc[rt][n] = __builtin_amdgcn_mfma_f32_16x16x32_bf16(
                            a[rt][kk], b[n][kk], acc[rt][n], 0, 0, 0);
                }
            if (p) __syncthreads();
            #pragma unroll
            for (int rt = 0; rt < 2; ++rt)
                #pragma unroll
                for (int n = 0; n < 4; ++n)
                    #pragma unroll
                    for (int r = 0; r < 4; ++r) {
                        int row = m0 + rt * 16 + (lane >> 4) * 4 + r;
                        Cs[row * 68 + n * 16 + (lane & 15)] = f2bf_raw(acc[rt][n][r]);
                    }
            __syncthreads();
            // fp8 epilogue: 128 rows x 8 chunks(8ch) = 1024 units -> 4 iters
            #pragma unroll
            for (int i = 0; i < 4; ++i) {
                int idx = t + 256 * i;
                int row = idx >> 3, c8 = idx & 7;
                if (r0 + row < nrows) {
                    uint2 va = *reinterpret_cast<const uint2*>(&Cs[row * 68 + c8 * 8]);
                    uint2 vb = *reinterpret_cast<const uint2*>(&Cs[row * 68 + c8 * 8 + 4]);
                    int w0 = __builtin_amdgcn_cvt_pk_fp8_f32(lo_f(va.x), hi_f(va.x), 0, false);
                    w0 = __builtin_amdgcn_cvt_pk_fp8_f32(lo_f(va.y), hi_f(va.y), w0, true);
                    int w1 = __builtin_amdgcn_cvt_pk_fp8_f32(lo_f(vb.x), hi_f(vb.x), 0, false);
                    w1 = __builtin_amdgcn_cvt_pk_fp8_f32(lo_f(vb.y), hi_f(vb.y), w1, true);
                    *reinterpret_cast<uint2*>(Hf8 + (size_t)(r0 + row) * 128 + p * 64 + c8 * 8) =
                        make_uint2((unsigned)w0, (unsigned)w1);
                }
            }
            if (!p) __syncthreads();
        }
    } else {
        // ---- ms_scatter role: bin edges into per-bucket chunks (packed = (dst&255)<<24 | src)
        int* cnt = (int*)smem;              // [MAXBUK]
        int* gbase = (int*)(smem + 4096);   // [MAXBUK]
        const int e0 = ((int)blockIdx.x - gb) * 4096;
        const int e1 = min(E, e0 + 4096);
        for (int b = t; b < nbuk; b += 256) cnt[b] = 0;
        __syncthreads();
        for (int e = e0 + t; e < e1; e += 256) atomicAdd(&cnt[dst[e] >> 8], 1);
        __syncthreads();
        for (int b = t; b < nbuk; b += 256) {
            int c = cnt[b];
            gbase[b] = c ? atomicAdd(&bcur[b], c) : 0;
            cnt[b] = 0;
        }
        __syncthreads();
        for (int e = e0 + t; e < e1; e += 256) {
            int d = dst[e];
            int b = d >> 8;
            int r = atomicAdd(&cnt[b], 1);
            packed[gbase[b] + r] = ((unsigned)(d & 255) << 24) | (unsigned)src[e];
        }
    }
}

// 4) csr_fine2: per-node nmeta {base,deg} + dinv; place edge src ids into epack[pos].x.
__global__ __launch_bounds__(256) void csr_fine2_kernel(const unsigned* __restrict__ packed,
                                                        const int* __restrict__ bofs,
                                                        uint2* __restrict__ nmeta,
                                                        float* __restrict__ dinv,
                                                        unsigned* __restrict__ epu, int n) {
    __shared__ int cnt2[NPB];
    __shared__ int cur[NPB];
    const int t = threadIdx.x;
    const int b = blockIdx.x;
    const int node0 = b << 8;
    const int nn = min(NPB, n - node0);
    cnt2[t] = 0;
    __syncthreads();
    const int beg = bofs[b], end = bofs[b + 1];
    for (int i = beg + t; i < end; i += 256) atomicAdd(&cnt2[packed[i] >> 24], 1);
    __syncthreads();
    int c = cnt2[t];
    cur[t] = c;
    __syncthreads();
    for (int o = 1; o < 256; o <<= 1) {        // inclusive scan over 256 local counts
        int u = (t >= o) ? cur[t - o] : 0;
        __syncthreads();
        cur[t] += u;
        __syncthreads();
    }
    const int base = beg + cur[t] - c;          // exclusive
    if (t < nn) {
        nmeta[node0 + t] = make_uint2((unsigned)base, (unsigned)c);
        dinv[node0 + t] = rsqrtf((float)(c + 1));
    }
    __syncthreads();
    cur[t] = base;
    __syncthreads();
    for (int i = beg + t; i < end; i += 256) {
        unsigned u = packed[i];
        int pos = atomicAdd(&cur[u >> 24], 1);
        epu[2 * pos] = u & 0xFFFFFFu;           // epack[pos].x = src
    }
}

// 5) epw: fill epack[j].y = bits(dinv[src_j]).
__global__ __launch_bounds__(256) void epw_kernel(unsigned* __restrict__ epu,
                                                  const float* __restrict__ dinv, int E) {
    int i = blockIdx.x * 256 + threadIdx.x;
    if (i < E) {
        unsigned s = epu[2 * i];
        float w = dinv[s];
        unsigned wb; __builtin_memcpy(&wb, &w, 4);
        epu[2 * i + 1] = wb;
    }
}

// ---------------- Aggregation v9 (layer 1): fp8 gather, 4 groups x 16 subs, 2-level reduce ----
// v8 lesson: the af[16] x 3-level cross-group reduce (96 inst/node) dominated per-node VALU.
// 4 groups x 16 subs (8B dwordx2 gathers) halves lane state -> af[8], 2 levels = 32 inst/node.

__device__ __forceinline__ float epw_f(uint2 e) {
    float w; __builtin_memcpy(&w, &e.y, 4); return w;
}

__device__ __forceinline__ void accf8_2(f32x2* acc, uint2 v, float w) {
    f32x2 wv = {w, w};
    acc[0] += __builtin_amdgcn_cvt_pk_f32_fp8(v.x, false) * wv;
    acc[1] += __builtin_amdgcn_cvt_pk_f32_fp8(v.x, true)  * wv;
    acc[2] += __builtin_amdgcn_cvt_pk_f32_fp8(v.y, false) * wv;
    acc[3] += __builtin_amdgcn_cvt_pk_f32_fp8(v.y, true)  * wv;
}

__global__ __launch_bounds__(128) void agg128_v9(const uint2* __restrict__ H2,
                                                 const uint2* __restrict__ nmeta,
                                                 const uint2* __restrict__ epack,
                                                 const float* __restrict__ biasf,
                                                 uint4* __restrict__ G4, int n) {
    const int lane = threadIdx.x & 63;
    const int g = lane >> 4;          // 4 edge groups
    const int sub = lane & 15;        // 8B chunk of the 128B fp8 row (8 channels)
    const int node = blockIdx.x * 2 + (threadIdx.x >> 6);
    if (node >= n) return;

    uint2 vself = H2[((unsigned)node << 4) + (unsigned)sub];

    const uint2 meta = nmeta[node];
    const int base = (int)meta.x;
    const int cnt = (int)meta.y;
    const int end = base + cnt;
    const float di = rsqrtf((float)(cnt + 1));

    f32x2 acc[4];
    #pragma unroll
    for (int i = 0; i < 4; ++i) acc[i] = (f32x2){0.f, 0.f};
    accf8_2(acc, vself, (g == 0) ? di : 0.f);   // di-factored self term

    int j = base;
    for (; j + 15 < end; j += 16) {             // 16 edges, 4 gathers/lane in flight
        uint2 e0 = epack[j + g];
        uint2 e1 = epack[j + 4 + g];
        uint2 e2 = epack[j + 8 + g];
        uint2 e3 = epack[j + 12 + g];
        uint2 v0 = H2[(e0.x << 4) + (unsigned)sub];
        uint2 v1 = H2[(e1.x << 4) + (unsigned)sub];
        uint2 v2 = H2[(e2.x << 4) + (unsigned)sub];
        uint2 v3 = H2[(e3.x << 4) + (unsigned)sub];
        accf8_2(acc, v0, epw_f(e0));
        accf8_2(acc, v1, epw_f(e1));
        accf8_2(acc, v2, epw_f(e2));
        accf8_2(acc, v3, epw_f(e3));
    }
    for (; j + 7 < end; j += 8) {               // 8 edges
        uint2 e0 = epack[j + g];
        uint2 e1 = epack[j + 4 + g];
        uint2 v0 = H2[(e0.x << 4) + (unsigned)sub];
        uint2 v1 = H2[(e1.x << 4) + (unsigned)sub];
        accf8_2(acc, v0, epw_f(e0));
        accf8_2(acc, v1, epw_f(e1));
    }
    for (; j + 3 < end; j += 4) {               // 4 edges
        uint2 e0 = epack[j + g];
        uint2 v0 = H2[(e0.x << 4) + (unsigned)sub];
        accf8_2(acc, v0, epw_f(e0));
    }
    if (j + g < end) {                          // tail (<4 edges), group-predicated
        uint2 e0 = epack[j + g];
        uint2 v0 = H2[(e0.x << 4) + (unsigned)sub];
        accf8_2(acc, v0, epw_f(e0));
    }

    float a8[8];
    #pragma unroll
    for (int i = 0; i < 4; ++i) { a8[2 * i] = acc[i].x; a8[2 * i + 1] = acc[i].y; }
    #pragma unroll
    for (int i = 0; i < 8; ++i) {               // combine the 4 edge-groups (lane bits 4,5)
        a8[i] += __shfl_xor(a8[i], 16, 64);
        a8[i] += __shfl_xor(a8[i], 32, 64);
    }

    if (g == 0) {                               // lanes 0..15: channels [sub*8, sub*8+8)
        const float4* b4 = (const float4*)biasf;
        float4 blo = b4[sub * 2], bhi = b4[sub * 2 + 1];
        a8[0] = fmaxf(fmaf(di, a8[0], blo.x), 0.f);
        a8[1] = fmaxf(fmaf(di, a8[1], blo.y), 0.f);
        a8[2] = fmaxf(fmaf(di, a8[2], blo.z), 0.f);
        a8[3] = fmaxf(fmaf(di, a8[3], blo.w), 0.f);
        a8[4] = fmaxf(fmaf(di, a8[4], bhi.x), 0.f);
        a8[5] = fmaxf(fmaf(di, a8[5], bhi.y), 0.f);
        a8[6] = fmaxf(fmaf(di, a8[6], bhi.z), 0.f);
        a8[7] = fmaxf(fmaf(di, a8[7], bhi.w), 0.f);
        uint4 o;
        o.x = (unsigned)f2bf_raw(a8[0]) | ((unsigned)f2bf_raw(a8[1]) << 16);
        o.y = (unsigned)f2bf_raw(a8[2]) | ((unsigned)f2bf_raw(a8[3]) << 16);
        o.z = (unsigned)f2bf_raw(a8[4]) | ((unsigned)f2bf_raw(a8[5]) << 16);
        o.w = (unsigned)f2bf_raw(a8[6]) | ((unsigned)f2bf_raw(a8[7]) << 16);
        G4[((unsigned)node << 4) + (unsigned)sub] = o;    // G1 bf16 row-major, 16B/lane
    }
}

// ---------------- GEMM2b (MFMA): T[nrows x 64] = G1 * W2, bf16 out, NO bias ----------------

__global__ __launch_bounds__(256) void gemm2b_mfma(const unsigned short* __restrict__ X,
                                                   const unsigned short* __restrict__ WB2,
                                                   unsigned short* __restrict__ T, int nrows) {
    __shared__ __align__(16) unsigned short Xs[128 * 136];
    __shared__ __align__(16) unsigned short Cs[128 * 68];
    const int t = threadIdx.x;
    const int r0 = blockIdx.x * 128;

    const uint4* Xg = (const uint4*)X;
    #pragma unroll
    for (int i = 0; i < 8; ++i) {
        int idx = t + 256 * i;
        int row = idx >> 4, c8 = idx & 15;
        uint4 v = {0u, 0u, 0u, 0u};
        if (r0 + row < nrows) v = Xg[(size_t)(r0 + row) * 16 + c8];
        *reinterpret_cast<uint4*>(&Xs[row * 136 + c8 * 8]) = v;
    }
    __syncthreads();

    const int lane = t & 63, w = t >> 6;
    const int m0 = w * 32;
    short8 a[2][4];
    #pragma unroll
    for (int rt = 0; rt < 2; ++rt)
        #pragma unroll
        for (int kk = 0; kk < 4; ++kk)
            a[rt][kk] = *reinterpret_cast<const short8*>(
                &Xs[(m0 + rt * 16 + (lane & 15)) * 136 + kk * 32 + (lane >> 4) * 8]);

    short8 b[4][4];
    #pragma unroll
    for (int n = 0; n < 4; ++n)
        #pragma unroll
        for (int kk = 0; kk < 4; ++kk)
            b[n][kk] = *reinterpret_cast<const short8*>(
                WB2 + (size_t)((n * 4 + kk) * 64 + lane) * 8);

    f32x4 acc[2][4];
    #pragma unroll
    for (int rt = 0; rt < 2; ++rt)
        #pragma unroll
        for (int n = 0; n < 4; ++n) {
            acc[rt][n] = (f32x4){0.f, 0.f, 0.f, 0.f};
            #pragma unroll
            for (int kk = 0; kk < 4; ++kk)
                acc[rt][n] = __builtin_amdgcn_mfma_f32_16x16x32_bf16(
                    a[rt][kk], b[n][kk], acc[rt][n], 0, 0, 0);
        }

    __syncthreads();
    #pragma unroll
    for (int rt = 0; rt < 2; ++rt)
        #pragma unroll
        for (int n = 0; n < 4; ++n)
            #pragma unroll
            for (int r = 0; r < 4; ++r) {
                int row = m0 + rt * 16 + (lane >> 4) * 4 + r;
                Cs[row * 68 + n * 16 + (lane & 15)] = f2bf_raw(acc[rt][n][r]);
            }
    __syncthreads();
    #pragma unroll
    for (int i = 0; i < 8; ++i) {
        int idx = t + 256 * i;
        int row = idx >> 4, c4 = idx & 15;
        if (r0 + row < nrows) {
            uint2 v = *reinterpret_cast<const uint2*>(&Cs[row * 68 + c4 * 4]);
            *reinterpret_cast<uint2*>(T + (size_t)(r0 + row) * 64 + c4 * 4) = v;
        }
    }
}

// ---------------- Aggregation 2 + bias + log_softmax (64 ch, row-major bf16 T) ----------------

__device__ __forceinline__ void acc8v(f32x2* acc, uint4 v, float w) {
    f32x2 wv = {w, w};
    acc[0] += (f32x2){lo_f(v.x), hi_f(v.x)} * wv;
    acc[1] += (f32x2){lo_f(v.y), hi_f(v.y)} * wv;
    acc[2] += (f32x2){lo_f(v.z), hi_f(v.z)} * wv;
    acc[3] += (f32x2){lo_f(v.w), hi_f(v.w)} * wv;
}

__global__ __launch_bounds__(128) void agg64_final(const uint4* __restrict__ T4,
                                                   const uint2* __restrict__ nmeta,
                                                   const uint2* __restrict__ epack,
                                                   const float* __restrict__ b2f,
                                                   void* __restrict__ OUTv, int n,
                                                   const int* __restrict__ flag) {
    const int lane = threadIdx.x & 63;
    const int g = lane >> 3;
    const int sub = lane & 7;
    const int node = blockIdx.x * 2 + (threadIdx.x >> 6);
    if (node >= n) return;
    const int outf32 = *flag;

    const unsigned selfoff = ((unsigned)node << 3) + (unsigned)sub;
    uint4 vself = T4[selfoff];

    const uint2 meta = nmeta[node];
    const int base = (int)meta.x;
    const int cnt = (int)meta.y;
    const int end = base + cnt;
    const float di = rsqrtf((float)(cnt + 1));

    f32x2 acc[4];
    {
        const float ws = (g == 0) ? di : 0.f;   // di-factored
        acc[0] = (f32x2){ws * lo_f(vself.x), ws * hi_f(vself.x)};
        acc[1] = (f32x2){ws * lo_f(vself.y), ws * hi_f(vself.y)};
        acc[2] = (f32x2){ws * lo_f(vself.z), ws * hi_f(vself.z)};
        acc[3] = (f32x2){ws * lo_f(vself.w), ws * hi_f(vself.w)};
    }

    int j = base;
    for (; j + 15 < end; j += 16) {          // 16 edges, 2 gathers per lane in flight
        uint2 e0 = epack[j + g];
        uint2 e1 = epack[j + 8 + g];
        uint4 v0 = T4[(e0.x << 3) + (unsigned)sub];
        uint4 v1 = T4[(e1.x << 3) + (unsigned)sub];
        acc8v(acc, v0, epw_f(e0));
        acc8v(acc, v1, epw_f(e1));
    }
    for (; j + 7 < end; j += 8) {            // 8 edges
        uint2 e0 = epack[j + g];
        uint4 v0 = T4[(e0.x << 3) + (unsigned)sub];
        acc8v(acc, v0, epw_f(e0));
    }
    if (j + g < end) {                       // tail (<8 edges), group-predicated
        uint2 e0 = epack[j + g];
        uint4 v0 = T4[(e0.x << 3) + (unsigned)sub];
        acc8v(acc, v0, epw_f(e0));
    }

    float a8[8];
    #pragma unroll
    for (int i = 0; i < 4; ++i) { a8[2 * i] = acc[i].x; a8[2 * i + 1] = acc[i].y; }
    #pragma unroll
    for (int i = 0; i < 8; ++i) {            // combine the 8 edge-groups
        a8[i] += __shfl_xor(a8[i], 8, 64);
        a8[i] += __shfl_xor(a8[i], 16, 64);
        a8[i] += __shfl_xor(a8[i], 32, 64);
    }

    if (g == 0) {                            // lanes 0..7 hold the full 64-ch row
        const float4* b4 = (const float4*)b2f;
        float4 blo = b4[sub * 2], bhi = b4[sub * 2 + 1];
        a8[0] = fmaf(di, a8[0], blo.x);
        a8[1] = fmaf(di, a8[1], blo.y);
        a8[2] = fmaf(di, a8[2], blo.z);
        a8[3] = fmaf(di, a8[3], blo.w);
        a8[4] = fmaf(di, a8[4], bhi.x);
        a8[5] = fmaf(di, a8[5], bhi.y);
        a8[6] = fmaf(di, a8[6], bhi.z);
        a8[7] = fmaf(di, a8[7], bhi.w);

        float m = fmaxf(fmaxf(fmaxf(a8[0], a8[1]), fmaxf(a8[2], a8[3])),
                        fmaxf(fmaxf(a8[4], a8[5]), fmaxf(a8[6], a8[7])));
        m = fmaxf(m, __shfl_xor(m, 1, 64));
        m = fmaxf(m, __shfl_xor(m, 2, 64));
        m = fmaxf(m, __shfl_xor(m, 4, 64));
        float s = __expf(a8[0] - m) + __expf(a8[1] - m) + __expf(a8[2] - m) + __expf(a8[3] - m) +
                  __expf(a8[4] - m) + __expf(a8[5] - m) + __expf(a8[6] - m) + __expf(a8[7] - m);
        s += __shfl_xor(s, 1, 64);
        s += __shfl_xor(s, 2, 64);
        s += __shfl_xor(s, 4, 64);
        const float lse = m + __logf(s);

        if (outf32) {
            float4* Of = (float4*)OUTv;
            float4 o0 = {a8[0] - lse, a8[1] - lse, a8[2] - lse, a8[3] - lse};
            float4 o1 = {a8[4] - lse, a8[5] - lse, a8[6] - lse, a8[7] - lse};
            Of[(size_t)node * 16 + sub * 2] = o0;
            Of[(size_t)node * 16 + sub * 2 + 1] = o1;
        } else {
            uint4 o;
            o.x = (unsigned)f2bf_raw(a8[0] - lse) | ((unsigned)f2bf_raw(a8[1] - lse) << 16);
            o.y = (unsigned)f2bf_raw(a8[2] - lse) | ((unsigned)f2bf_raw(a8[3] - lse) << 16);
            o.z = (unsigned)f2bf_raw(a8[4] - lse) | ((unsigned)f2bf_raw(a8[5] - lse) << 16);
            o.w = (unsigned)f2bf_raw(a8[6] - lse) | ((unsigned)f2bf_raw(a8[7] - lse) << 16);
            ((uint4*)OUTv)[(size_t)node * 8 + sub] = o;
        }
    }
}

// ---------------- launch ----------------

extern "C" void kernel_launch(void* const* d_in, const int* in_sizes, int n_in,
                              void* d_out, int out_size, void* d_ws, size_t ws_size,
                              hipStream_t stream) {
    const void* x  = d_in[0];
    const int*  ei = (const int*)d_in[1];
    const void* W1 = d_in[2];
    const void* b1 = d_in[3];
    const void* W2 = d_in[4];
    const void* b2 = d_in[5];

    const int N = in_sizes[0] / 128;
    const int E = in_sizes[1] / 2;
    const int* src = ei;
    const int* dst = ei + E;
    const int NBUK = (N + NPB - 1) / NPB;     // 391 for N=100K

    char* p = (char*)d_ws;
    auto alloc = [&](size_t bytes) { char* q = p; p += (bytes + 255) & ~255ull; return q; };
    int*   flag   = (int*)  alloc(4);
    uint2* nmeta  = (uint2*)alloc((size_t)N * 8);
    float* dinv   = (float*)alloc((size_t)N * 4);
    int*   bktcnt = (int*)  alloc((size_t)NBUK * 4);
    int*   bofs   = (int*)  alloc((size_t)(NBUK + 1) * 4);
    int*   bcur   = (int*)  alloc((size_t)NBUK * 4);
    float* b1f    = (float*)alloc(128 * 4);
    float* b2f    = (float*)alloc(64 * 4);
    unsigned short* WB1 = (unsigned short*)alloc(16384 * 2);
    unsigned short* WB2 = (unsigned short*)alloc(8192 * 2);
    unsigned* big = (unsigned*)alloc((size_t)N * 128 * 2);   // H fp8 (12.8 MB), later T bf16 (12.8 MB)
    unsigned* packed = (unsigned*)d_out;          // 6.4 MB scratch in d_out (dead after csr_fine2)
    uint2*    epack  = (uint2*)d_in[1];           // {src, w_bits}; overwrites src+dst (dead after fatB scatter)
    unsigned* g1 = (unsigned*)d_in[0];            // G1 bf16 row-major into x's buffer (x dead after gemm1)
    unsigned short* T = (unsigned short*)big;     // T (row-major bf16) overwrites H fp8 (dead after agg1)
    (void)ws_size; (void)n_in; (void)out_size;

    const int PREPB = 97;                     // covers 24768 prep threads
    const int MSB = (E + 4095) / 4096;
    const int GB = (N + 127) / 128;

    hipMemsetAsync(bktcnt, 0, (size_t)NBUK * 4, stream);
    fatA_kernel<<<PREPB + MSB, 256, 0, stream>>>((const unsigned short*)W1, W1, W2, b1, b2,
                                                 WB1, WB2, b1f, b2f, flag, in_sizes[2],
                                                 dst, bktcnt, E, NBUK, PREPB);
    bscan_kernel<<<1, 1024, 0, stream>>>(bktcnt, bofs, bcur, NBUK, E);
    fatB_kernel<<<GB + MSB, 256, 0, stream>>>(x, WB1, (unsigned char*)big, N, flag,
                                              src, dst, bcur, packed, E, NBUK, GB);
    csr_fine2_kernel<<<NBUK, 256, 0, stream>>>(packed, bofs, nmeta, dinv, (unsigned*)epack, N);
    epw_kernel<<<(E + 255) / 256, 256, 0, stream>>>((unsigned*)epack, dinv, E);

    agg128_v9<<<(N + 1) / 2, 128, 0, stream>>>((const uint2*)big, nmeta, epack, b1f, (uint4*)g1, N);
    gemm2b_mfma<<<GB, 256, 0, stream>>>((const unsigned short*)g1, WB2, T, N);
    agg64_final<<<(N + 1) / 2, 128, 0, stream>>>((const uint4*)T, nmeta, epack, b2f, d_out, N, flag);
}

// Round 11
// 294.017 us; speedup vs baseline: 1.6602x; 1.0179x over previous
//
#include <hip/hip_runtime.h>
#include <hip/hip_bf16.h>

typedef __hip_bfloat16 bf16;
typedef short short8 __attribute__((ext_vector_type(8)));
typedef float f32x4 __attribute__((ext_vector_type(4)));
typedef float f32x2 __attribute__((ext_vector_type(2)));

#define NPB 256          // nodes per bucket (coarse radix = dst>>8)
#define MAXBUK 1024      // supports N <= 262144

__device__ __forceinline__ float bf2f_raw(unsigned short u) {
    unsigned x = ((unsigned)u) << 16; float f; __builtin_memcpy(&f, &x, 4); return f;
}
__device__ __forceinline__ unsigned short f2bf_raw(float f) {   // RNE
    unsigned u; __builtin_memcpy(&u, &f, 4);
    u += 0x7FFFu + ((u >> 16) & 1u);
    return (unsigned short)(u >> 16);
}
__device__ __forceinline__ float lo_f(unsigned u) {
    unsigned x = u << 16; float f; __builtin_memcpy(&f, &x, 4); return f;
}
__device__ __forceinline__ float hi_f(unsigned u) {
    unsigned x = u & 0xffff0000u; float f; __builtin_memcpy(&f, &x, 4); return f;
}

// ---------------- fatA: prep role (sniff + weight repack + bias conv) || ms_count role ----------

__global__ __launch_bounds__(256) void fatA_kernel(const unsigned short* __restrict__ W1s,
                                                   const void* __restrict__ W1p,
                                                   const void* __restrict__ W2p,
                                                   const void* __restrict__ b1p,
                                                   const void* __restrict__ b2p,
                                                   unsigned short* __restrict__ WB1,
                                                   unsigned short* __restrict__ WB2,
                                                   float* __restrict__ b1f,
                                                   float* __restrict__ b2f,
                                                   int* __restrict__ flag, int nshorts,
                                                   const int* __restrict__ dst,
                                                   int* __restrict__ bktcnt,
                                                   int E, int nbuk, int prepb) {
    __shared__ int smem[MAXBUK];
    const int tt = threadIdx.x;
    if ((int)blockIdx.x < prepb) {
        const int sample = min(nshorts, 2048);
        int c = 0;
        for (int i = tt; i < sample; i += 256) {
            unsigned e = (W1s[i] >> 7) & 0xFFu;
            if (e >= 140u || (e >= 1u && e <= 40u)) c++;
        }
        smem[tt] = c;
        __syncthreads();
        for (int o = 128; o > 0; o >>= 1) {
            if (tt < o) smem[tt] += smem[tt + o];
            __syncthreads();
        }
        const int isf32 = (smem[0] > sample / 8) ? 1 : 0;
        if (blockIdx.x == 0 && tt == 0) *flag = isf32;

        const int t = blockIdx.x * 256 + tt;
        const int T1 = 16384, T2 = 8192;
        if (t < T1) {
            int j = t & 7, l = (t >> 3) & 63, f = t >> 9;
            int n = f >> 2, kk = f & 3;
            int k = kk * 32 + (l >> 4) * 8 + j;
            int col = n * 16 + (l & 15);
            WB1[t] = isf32 ? f2bf_raw(((const float*)W1p)[k * 128 + col])
                           : ((const unsigned short*)W1p)[k * 128 + col];
        } else if (t < T1 + T2) {
            int o = t - T1;
            int j = o & 7, l = (o >> 3) & 63, f = o >> 9;
            int n = f >> 2, kk = f & 3;
            int k = kk * 32 + (l >> 4) * 8 + j;
            int col = n * 16 + (l & 15);
            WB2[o] = isf32 ? f2bf_raw(((const float*)W2p)[k * 64 + col])
                           : ((const unsigned short*)W2p)[k * 64 + col];
        } else if (t < T1 + T2 + 128) {
            int o = t - T1 - T2;
            b1f[o] = isf32 ? ((const float*)b1p)[o] : bf2f_raw(((const unsigned short*)b1p)[o]);
        } else if (t < T1 + T2 + 192) {
            int o = t - T1 - T2 - 128;
            b2f[o] = isf32 ? ((const float*)b2p)[o] : bf2f_raw(((const unsigned short*)b2p)[o]);
        }
    } else {
        const int e0 = ((int)blockIdx.x - prepb) * 4096;
        const int e1 = min(E, e0 + 4096);
        for (int b = tt; b < nbuk; b += 256) smem[b] = 0;
        __syncthreads();
        for (int e = e0 + tt; e < e1; e += 256) atomicAdd(&smem[dst[e] >> 8], 1);
        __syncthreads();
        for (int b = tt; b < nbuk; b += 256) {
            int c = smem[b];
            if (c) atomicAdd(&bktcnt[b], c);
        }
    }
}

// 2) bscan: exclusive scan of bucket totals -> bofs/bcur.
__global__ __launch_bounds__(1024) void bscan_kernel(const int* __restrict__ bktcnt,
                                                     int* __restrict__ bofs,
                                                     int* __restrict__ bcur,
                                                     int nbuk, int total) {
    __shared__ int ps[1024];
    const int t = threadIdx.x;
    int v = (t < nbuk) ? bktcnt[t] : 0;
    ps[t] = v;
    __syncthreads();
    for (int o = 1; o < 1024; o <<= 1) {
        int u = (t >= o) ? ps[t - o] : 0;
        __syncthreads();
        ps[t] += u;
        __syncthreads();
    }
    if (t < nbuk) {
        int ex = ps[t] - v;
        bofs[t] = ex;
        bcur[t] = ex;
    }
    if (t == 0) bofs[nbuk] = total;
}

// ---------------- fatB: gemm1 (fp8-out) role || ms_scatter role ----------------
// LDS diet (round-11): Xs and Cs UNIONED -- after A-fragments are in registers, Xs is dead.
// 52224 -> 34816 bytes => 4 blocks/CU (was 3), raising the occupancy cap 37.5% -> 50%.

__global__ __launch_bounds__(256) void fatB_kernel(const void* __restrict__ Xp,
                                                   const unsigned short* __restrict__ WB1,
                                                   unsigned char* __restrict__ Hf8, int nrows,
                                                   const int* __restrict__ flag,
                                                   const int* __restrict__ src,
                                                   const int* __restrict__ dst,
                                                   int* __restrict__ bcur,
                                                   unsigned* __restrict__ packed,
                                                   int E, int nbuk, int gb) {
    __shared__ __align__(16) char smem[34816];   // union: Xs[128][136]s | Cs[128][68]s | scatter {cnt,gbase}
    const int t = threadIdx.x;
    if ((int)blockIdx.x < gb) {
        unsigned short* Xs = (unsigned short*)smem;   // [128][136]
        unsigned short* Cs = (unsigned short*)smem;   // [128][68] (overlays Xs after barrier)
        const int r0 = blockIdx.x * 128;
        const int isf32 = *flag;

        if (isf32) {
            const float4* Xg = (const float4*)Xp;
            #pragma unroll
            for (int i = 0; i < 16; ++i) {
                int idx = t + 256 * i;
                int row = idx >> 5, c4 = idx & 31;
                float4 v = {0.f, 0.f, 0.f, 0.f};
                if (r0 + row < nrows) v = Xg[(size_t)(r0 + row) * 32 + c4];
                unsigned lo = (unsigned)f2bf_raw(v.x) | ((unsigned)f2bf_raw(v.y) << 16);
                unsigned hi = (unsigned)f2bf_raw(v.z) | ((unsigned)f2bf_raw(v.w) << 16);
                *reinterpret_cast<uint2*>(&Xs[row * 136 + c4 * 4]) = make_uint2(lo, hi);
            }
        } else {
            const uint4* Xg = (const uint4*)Xp;
            #pragma unroll
            for (int i = 0; i < 8; ++i) {
                int idx = t + 256 * i;
                int row = idx >> 4, c8 = idx & 15;
                uint4 v = {0u, 0u, 0u, 0u};
                if (r0 + row < nrows) v = Xg[(size_t)(r0 + row) * 16 + c8];
                *reinterpret_cast<uint4*>(&Xs[row * 136 + c8 * 8]) = v;
            }
        }
        __syncthreads();

        const int lane = t & 63, w = t >> 6;
        const int m0 = w * 32;
        short8 a[2][4];
        #pragma unroll
        for (int rt = 0; rt < 2; ++rt)
            #pragma unroll
            for (int kk = 0; kk < 4; ++kk)
                a[rt][kk] = *reinterpret_cast<const short8*>(
                    &Xs[(m0 + rt * 16 + (lane & 15)) * 136 + kk * 32 + (lane >> 4) * 8]);
        __syncthreads();          // Xs dead beyond this point; Cs may overlay it

        for (int p = 0; p < 2; ++p) {
            short8 b[4][4];
            #pragma unroll
            for (int n = 0; n < 4; ++n)
                #pragma unroll
                for (int kk = 0; kk < 4; ++kk)
                    b[n][kk] = *reinterpret_cast<const short8*>(
                        WB1 + (size_t)(((p * 4 + n) * 4 + kk) * 64 + lane) * 8);
            f32x4 acc[2][4];
            #pragma unroll
            for (int rt = 0; rt < 2; ++rt)
                #pragma unroll
                for (int n = 0; n < 4; ++n) {
                    acc[rt][n] = (f32x4){0.f, 0.f, 0.f, 0.f};
                    #pragma unroll
                    for (int kk = 0; kk < 4; ++kk)
                        acc[rt][n] = __builtin_amdgcn_mfma_f32_16x16x32_bf16(
                            a[rt][kk], b[n][kk], acc[rt][n], 0, 0, 0);
                }
            if (p) __syncthreads();
            #pragma unroll
            for (int rt = 0; rt < 2; ++rt)
                #pragma unroll
                for (int n = 0; n < 4; ++n)
                    #pragma unroll
                    for (int r = 0; r < 4; ++r) {
                        int row = m0 + rt * 16 + (lane >> 4) * 4 + r;
                        Cs[row * 68 + n * 16 + (lane & 15)] = f2bf_raw(acc[rt][n][r]);
                    }
            __syncthreads();
            // fp8 epilogue: 128 rows x 8 chunks(8ch) = 1024 units -> 4 iters
            #pragma unroll
            for (int i = 0; i < 4; ++i) {
                int idx = t + 256 * i;
                int row = idx >> 3, c8 = idx & 7;
                if (r0 + row < nrows) {
                    uint2 va = *reinterpret_cast<const uint2*>(&Cs[row * 68 + c8 * 8]);
                    uint2 vb = *reinterpret_cast<const uint2*>(&Cs[row * 68 + c8 * 8 + 4]);
                    int w0 = __builtin_amdgcn_cvt_pk_fp8_f32(lo_f(va.x), hi_f(va.x), 0, false);
                    w0 = __builtin_amdgcn_cvt_pk_fp8_f32(lo_f(va.y), hi_f(va.y), w0, true);
                    int w1 = __builtin_amdgcn_cvt_pk_fp8_f32(lo_f(vb.x), hi_f(vb.x), 0, false);
                    w1 = __builtin_amdgcn_cvt_pk_fp8_f32(lo_f(vb.y), hi_f(vb.y), w1, true);
                    *reinterpret_cast<uint2*>(Hf8 + (size_t)(r0 + row) * 128 + p * 64 + c8 * 8) =
                        make_uint2((unsigned)w0, (unsigned)w1);
                }
            }
            if (!p) __syncthreads();
        }
    } else {
        // ---- ms_scatter role
        int* cnt = (int*)smem;              // [MAXBUK]
        int* gbase = (int*)(smem + 4096);   // [MAXBUK]
        const int e0 = ((int)blockIdx.x - gb) * 4096;
        const int e1 = min(E, e0 + 4096);
        for (int b = t; b < nbuk; b += 256) cnt[b] = 0;
        __syncthreads();
        for (int e = e0 + t; e < e1; e += 256) atomicAdd(&cnt[dst[e] >> 8], 1);
        __syncthreads();
        for (int b = t; b < nbuk; b += 256) {
            int c = cnt[b];
            gbase[b] = c ? atomicAdd(&bcur[b], c) : 0;
            cnt[b] = 0;
        }
        __syncthreads();
        for (int e = e0 + t; e < e1; e += 256) {
            int d = dst[e];
            int b = d >> 8;
            int r = atomicAdd(&cnt[b], 1);
            packed[gbase[b] + r] = ((unsigned)(d & 255) << 24) | (unsigned)src[e];
        }
    }
}

// 4) csr_fine2: per-node nmeta {base,deg} + dinv; place edge src ids into epack[pos].x.
__global__ __launch_bounds__(256) void csr_fine2_kernel(const unsigned* __restrict__ packed,
                                                        const int* __restrict__ bofs,
                                                        uint2* __restrict__ nmeta,
                                                        float* __restrict__ dinv,
                                                        unsigned* __restrict__ epu, int n) {
    __shared__ int cnt2[NPB];
    __shared__ int cur[NPB];
    const int t = threadIdx.x;
    const int b = blockIdx.x;
    const int node0 = b << 8;
    const int nn = min(NPB, n - node0);
    cnt2[t] = 0;
    __syncthreads();
    const int beg = bofs[b], end = bofs[b + 1];
    for (int i = beg + t; i < end; i += 256) atomicAdd(&cnt2[packed[i] >> 24], 1);
    __syncthreads();
    int c = cnt2[t];
    cur[t] = c;
    __syncthreads();
    for (int o = 1; o < 256; o <<= 1) {        // inclusive scan over 256 local counts
        int u = (t >= o) ? cur[t - o] : 0;
        __syncthreads();
        cur[t] += u;
        __syncthreads();
    }
    const int base = beg + cur[t] - c;          // exclusive
    if (t < nn) {
        nmeta[node0 + t] = make_uint2((unsigned)base, (unsigned)c);
        dinv[node0 + t] = rsqrtf((float)(c + 1));
    }
    __syncthreads();
    cur[t] = base;
    __syncthreads();
    for (int i = beg + t; i < end; i += 256) {
        unsigned u = packed[i];
        int pos = atomicAdd(&cur[u >> 24], 1);
        epu[2 * pos] = u & 0xFFFFFFu;           // epack[pos].x = src
    }
}

// 5) epw: fill epack[j].y = bits(dinv[src_j]).
__global__ __launch_bounds__(256) void epw_kernel(unsigned* __restrict__ epu,
                                                  const float* __restrict__ dinv, int E) {
    int i = blockIdx.x * 256 + threadIdx.x;
    if (i < E) {
        unsigned s = epu[2 * i];
        float w = dinv[s];
        unsigned wb; __builtin_memcpy(&wb, &w, 4);
        epu[2 * i + 1] = wb;
    }
}

// ---------------- Aggregation v9 (layer 1): fp8 gather, 4 groups x 16 subs, 2-level reduce ----

__device__ __forceinline__ float epw_f(uint2 e) {
    float w; __builtin_memcpy(&w, &e.y, 4); return w;
}

__device__ __forceinline__ void accf8_2(f32x2* acc, uint2 v, float w) {
    f32x2 wv = {w, w};
    acc[0] += __builtin_amdgcn_cvt_pk_f32_fp8(v.x, false) * wv;
    acc[1] += __builtin_amdgcn_cvt_pk_f32_fp8(v.x, true)  * wv;
    acc[2] += __builtin_amdgcn_cvt_pk_f32_fp8(v.y, false) * wv;
    acc[3] += __builtin_amdgcn_cvt_pk_f32_fp8(v.y, true)  * wv;
}

__global__ __launch_bounds__(128) void agg128_v9(const uint2* __restrict__ H2,
                                                 const uint2* __restrict__ nmeta,
                                                 const uint2* __restrict__ epack,
                                                 const float* __restrict__ biasf,
                                                 uint4* __restrict__ G4, int n) {
    const int lane = threadIdx.x & 63;
    const int g = lane >> 4;          // 4 edge groups
    const int sub = lane & 15;        // 8B chunk of the 128B fp8 row (8 channels)
    const int node = blockIdx.x * 2 + (threadIdx.x >> 6);
    if (node >= n) return;

    uint2 vself = H2[((unsigned)node << 4) + (unsigned)sub];

    const uint2 meta = nmeta[node];
    const int base = (int)meta.x;
    const int cnt = (int)meta.y;
    const int end = base + cnt;
    const float di = rsqrtf((float)(cnt + 1));

    f32x2 acc[4];
    #pragma unroll
    for (int i = 0; i < 4; ++i) acc[i] = (f32x2){0.f, 0.f};
    accf8_2(acc, vself, (g == 0) ? di : 0.f);   // di-factored self term

    int j = base;
    for (; j + 15 < end; j += 16) {             // 16 edges, 4 gathers/lane in flight
        uint2 e0 = epack[j + g];
        uint2 e1 = epack[j + 4 + g];
        uint2 e2 = epack[j + 8 + g];
        uint2 e3 = epack[j + 12 + g];
        uint2 v0 = H2[(e0.x << 4) + (unsigned)sub];
        uint2 v1 = H2[(e1.x << 4) + (unsigned)sub];
        uint2 v2 = H2[(e2.x << 4) + (unsigned)sub];
        uint2 v3 = H2[(e3.x << 4) + (unsigned)sub];
        accf8_2(acc, v0, epw_f(e0));
        accf8_2(acc, v1, epw_f(e1));
        accf8_2(acc, v2, epw_f(e2));
        accf8_2(acc, v3, epw_f(e3));
    }
    for (; j + 7 < end; j += 8) {               // 8 edges
        uint2 e0 = epack[j + g];
        uint2 e1 = epack[j + 4 + g];
        uint2 v0 = H2[(e0.x << 4) + (unsigned)sub];
        uint2 v1 = H2[(e1.x << 4) + (unsigned)sub];
        accf8_2(acc, v0, epw_f(e0));
        accf8_2(acc, v1, epw_f(e1));
    }
    for (; j + 3 < end; j += 4) {               // 4 edges
        uint2 e0 = epack[j + g];
        uint2 v0 = H2[(e0.x << 4) + (unsigned)sub];
        accf8_2(acc, v0, epw_f(e0));
    }
    if (j + g < end) {                          // tail (<4 edges), group-predicated
        uint2 e0 = epack[j + g];
        uint2 v0 = H2[(e0.x << 4) + (unsigned)sub];
        accf8_2(acc, v0, epw_f(e0));
    }

    float a8[8];
    #pragma unroll
    for (int i = 0; i < 4; ++i) { a8[2 * i] = acc[i].x; a8[2 * i + 1] = acc[i].y; }
    #pragma unroll
    for (int i = 0; i < 8; ++i) {               // combine the 4 edge-groups (lane bits 4,5)
        a8[i] += __shfl_xor(a8[i], 16, 64);
        a8[i] += __shfl_xor(a8[i], 32, 64);
    }

    if (g == 0) {                               // lanes 0..15: channels [sub*8, sub*8+8)
        const float4* b4 = (const float4*)biasf;
        float4 blo = b4[sub * 2], bhi = b4[sub * 2 + 1];
        a8[0] = fmaxf(fmaf(di, a8[0], blo.x), 0.f);
        a8[1] = fmaxf(fmaf(di, a8[1], blo.y), 0.f);
        a8[2] = fmaxf(fmaf(di, a8[2], blo.z), 0.f);
        a8[3] = fmaxf(fmaf(di, a8[3], blo.w), 0.f);
        a8[4] = fmaxf(fmaf(di, a8[4], bhi.x), 0.f);
        a8[5] = fmaxf(fmaf(di, a8[5], bhi.y), 0.f);
        a8[6] = fmaxf(fmaf(di, a8[6], bhi.z), 0.f);
        a8[7] = fmaxf(fmaf(di, a8[7], bhi.w), 0.f);
        uint4 o;
        o.x = (unsigned)f2bf_raw(a8[0]) | ((unsigned)f2bf_raw(a8[1]) << 16);
        o.y = (unsigned)f2bf_raw(a8[2]) | ((unsigned)f2bf_raw(a8[3]) << 16);
        o.z = (unsigned)f2bf_raw(a8[4]) | ((unsigned)f2bf_raw(a8[5]) << 16);
        o.w = (unsigned)f2bf_raw(a8[6]) | ((unsigned)f2bf_raw(a8[7]) << 16);
        G4[((unsigned)node << 4) + (unsigned)sub] = o;    // G1 bf16 row-major, 16B/lane
    }
}

// ---------------- GEMM2b (MFMA): T[nrows x 64] = G1 * W2, bf16 out, NO bias ----------------
// Xs/Cs unioned (34816 B) as in fatB.

__global__ __launch_bounds__(256) void gemm2b_mfma(const unsigned short* __restrict__ X,
                                                   const unsigned short* __restrict__ WB2,
                                                   unsigned short* __restrict__ T, int nrows) {
    __shared__ __align__(16) char smem[34816];
    unsigned short* Xs = (unsigned short*)smem;   // [128][136]
    unsigned short* Cs = (unsigned short*)smem;   // [128][68] (overlays Xs after barrier)
    const int t = threadIdx.x;
    const int r0 = blockIdx.x * 128;

    const uint4* Xg = (const uint4*)X;
    #pragma unroll
    for (int i = 0; i < 8; ++i) {
        int idx = t + 256 * i;
        int row = idx >> 4, c8 = idx & 15;
        uint4 v = {0u, 0u, 0u, 0u};
        if (r0 + row < nrows) v = Xg[(size_t)(r0 + row) * 16 + c8];
        *reinterpret_cast<uint4*>(&Xs[row * 136 + c8 * 8]) = v;
    }
    __syncthreads();

    const int lane = t & 63, w = t >> 6;
    const int m0 = w * 32;
    short8 a[2][4];
    #pragma unroll
    for (int rt = 0; rt < 2; ++rt)
        #pragma unroll
        for (int kk = 0; kk < 4; ++kk)
            a[rt][kk] = *reinterpret_cast<const short8*>(
                &Xs[(m0 + rt * 16 + (lane & 15)) * 136 + kk * 32 + (lane >> 4) * 8]);
    __syncthreads();              // Xs dead; Cs overlays

    short8 b[4][4];
    #pragma unroll
    for (int n = 0; n < 4; ++n)
        #pragma unroll
        for (int kk = 0; kk < 4; ++kk)
            b[n][kk] = *reinterpret_cast<const short8*>(
                WB2 + (size_t)((n * 4 + kk) * 64 + lane) * 8);

    f32x4 acc[2][4];
    #pragma unroll
    for (int rt = 0; rt < 2; ++rt)
        #pragma unroll
        for (int n = 0; n < 4; ++n) {
            acc[rt][n] = (f32x4){0.f, 0.f, 0.f, 0.f};
            #pragma unroll
            for (int kk = 0; kk < 4; ++kk)
                acc[rt][n] = __builtin_amdgcn_mfma_f32_16x16x32_bf16(
                    a[rt][kk], b[n][kk], acc[rt][n], 0, 0, 0);
        }

    #pragma unroll
    for (int rt = 0; rt < 2; ++rt)
        #pragma unroll
        for (int n = 0; n < 4; ++n)
            #pragma unroll
            for (int r = 0; r < 4; ++r) {
                int row = m0 + rt * 16 + (lane >> 4) * 4 + r;
                Cs[row * 68 + n * 16 + (lane & 15)] = f2bf_raw(acc[rt][n][r]);
            }
    __syncthreads();
    #pragma unroll
    for (int i = 0; i < 8; ++i) {
        int idx = t + 256 * i;
        int row = idx >> 4, c4 = idx & 15;
        if (r0 + row < nrows) {
            uint2 v = *reinterpret_cast<const uint2*>(&Cs[row * 68 + c4 * 4]);
            *reinterpret_cast<uint2*>(T + (size_t)(r0 + row) * 64 + c4 * 4) = v;
        }
    }
}

// ---------------- Aggregation 2 v2: 4 groups x 16 subs (8B bf16), 2-level reduce + softmax ----

__device__ __forceinline__ void acc4v(f32x2* acc, uint2 v, float w) {
    f32x2 wv = {w, w};
    acc[0] += (f32x2){lo_f(v.x), hi_f(v.x)} * wv;
    acc[1] += (f32x2){lo_f(v.y), hi_f(v.y)} * wv;
}

__global__ __launch_bounds__(128) void agg64_final(const uint2* __restrict__ T2,
                                                   const uint2* __restrict__ nmeta,
                                                   const uint2* __restrict__ epack,
                                                   const float* __restrict__ b2f,
                                                   void* __restrict__ OUTv, int n,
                                                   const int* __restrict__ flag) {
    const int lane = threadIdx.x & 63;
    const int g = lane >> 4;          // 4 edge groups
    const int sub = lane & 15;        // 8B chunk (4 channels) of the 128B bf16 row
    const int node = blockIdx.x * 2 + (threadIdx.x >> 6);
    if (node >= n) return;
    const int outf32 = *flag;

    uint2 vself = T2[((unsigned)node << 4) + (unsigned)sub];

    const uint2 meta = nmeta[node];
    const int base = (int)meta.x;
    const int cnt = (int)meta.y;
    const int end = base + cnt;
    const float di = rsqrtf((float)(cnt + 1));

    f32x2 acc[2];
    {
        const float ws = (g == 0) ? di : 0.f;   // di-factored self term
        acc[0] = (f32x2){ws * lo_f(vself.x), ws * hi_f(vself.x)};
        acc[1] = (f32x2){ws * lo_f(vself.y), ws * hi_f(vself.y)};
    }

    int j = base;
    for (; j + 15 < end; j += 16) {             // 16 edges, 4 gathers/lane in flight
        uint2 e0 = epack[j + g];
        uint2 e1 = epack[j + 4 + g];
        uint2 e2 = epack[j + 8 + g];
        uint2 e3 = epack[j + 12 + g];
        uint2 v0 = T2[(e0.x << 4) + (unsigned)sub];
        uint2 v1 = T2[(e1.x << 4) + (unsigned)sub];
        uint2 v2 = T2[(e2.x << 4) + (unsigned)sub];
        uint2 v3 = T2[(e3.x << 4) + (unsigned)sub];
        acc4v(acc, v0, epw_f(e0));
        acc4v(acc, v1, epw_f(e1));
        acc4v(acc, v2, epw_f(e2));
        acc4v(acc, v3, epw_f(e3));
    }
    for (; j + 7 < end; j += 8) {               // 8 edges
        uint2 e0 = epack[j + g];
        uint2 e1 = epack[j + 4 + g];
        uint2 v0 = T2[(e0.x << 4) + (unsigned)sub];
        uint2 v1 = T2[(e1.x << 4) + (unsigned)sub];
        acc4v(acc, v0, epw_f(e0));
        acc4v(acc, v1, epw_f(e1));
    }
    for (; j + 3 < end; j += 4) {               // 4 edges
        uint2 e0 = epack[j + g];
        uint2 v0 = T2[(e0.x << 4) + (unsigned)sub];
        acc4v(acc, v0, epw_f(e0));
    }
    if (j + g < end) {                          // tail (<4 edges), group-predicated
        uint2 e0 = epack[j + g];
        uint2 v0 = T2[(e0.x << 4) + (unsigned)sub];
        acc4v(acc, v0, epw_f(e0));
    }

    float a4[4] = {acc[0].x, acc[0].y, acc[1].x, acc[1].y};
    #pragma unroll
    for (int i = 0; i < 4; ++i) {               // combine the 4 edge-groups (lane bits 4,5)
        a4[i] += __shfl_xor(a4[i], 16, 64);
        a4[i] += __shfl_xor(a4[i], 32, 64);
    }

    if (g == 0) {                               // lanes 0..15: channels [sub*4, sub*4+4)
        float4 bb = ((const float4*)b2f)[sub];
        a4[0] = fmaf(di, a4[0], bb.x);
        a4[1] = fmaf(di, a4[1], bb.y);
        a4[2] = fmaf(di, a4[2], bb.z);
        a4[3] = fmaf(di, a4[3], bb.w);

        float m = fmaxf(fmaxf(a4[0], a4[1]), fmaxf(a4[2], a4[3]));
        m = fmaxf(m, __shfl_xor(m, 1, 64));
        m = fmaxf(m, __shfl_xor(m, 2, 64));
        m = fmaxf(m, __shfl_xor(m, 4, 64));
        m = fmaxf(m, __shfl_xor(m, 8, 64));
        float s = __expf(a4[0] - m) + __expf(a4[1] - m) +
                  __expf(a4[2] - m) + __expf(a4[3] - m);
        s += __shfl_xor(s, 1, 64);
        s += __shfl_xor(s, 2, 64);
        s += __shfl_xor(s, 4, 64);
        s += __shfl_xor(s, 8, 64);
        const float lse = m + __logf(s);

        if (outf32) {
            float4 o = {a4[0] - lse, a4[1] - lse, a4[2] - lse, a4[3] - lse};
            ((float4*)OUTv)[(size_t)node * 16 + sub] = o;
        } else {
            uint2 o;
            o.x = (unsigned)f2bf_raw(a4[0] - lse) | ((unsigned)f2bf_raw(a4[1] - lse) << 16);
            o.y = (unsigned)f2bf_raw(a4[2] - lse) | ((unsigned)f2bf_raw(a4[3] - lse) << 16);
            ((uint2*)OUTv)[(size_t)node * 16 + sub] = o;
        }
    }
}

// ---------------- launch ----------------

extern "C" void kernel_launch(void* const* d_in, const int* in_sizes, int n_in,
                              void* d_out, int out_size, void* d_ws, size_t ws_size,
                              hipStream_t stream) {
    const void* x  = d_in[0];
    const int*  ei = (const int*)d_in[1];
    const void* W1 = d_in[2];
    const void* b1 = d_in[3];
    const void* W2 = d_in[4];
    const void* b2 = d_in[5];

    const int N = in_sizes[0] / 128;
    const int E = in_sizes[1] / 2;
    const int* src = ei;
    const int* dst = ei + E;
    const int NBUK = (N + NPB - 1) / NPB;     // 391 for N=100K

    char* p = (char*)d_ws;
    auto alloc = [&](size_t bytes) { char* q = p; p += (bytes + 255) & ~255ull; return q; };
    int*   flag   = (int*)  alloc(4);
    uint2* nmeta  = (uint2*)alloc((size_t)N * 8);
    float* dinv   = (float*)alloc((size_t)N * 4);
    int*   bktcnt = (int*)  alloc((size_t)NBUK * 4);
    int*   bofs   = (int*)  alloc((size_t)(NBUK + 1) * 4);
    int*   bcur   = (int*)  alloc((size_t)NBUK * 4);
    float* b1f    = (float*)alloc(128 * 4);
    float* b2f    = (float*)alloc(64 * 4);
    unsigned short* WB1 = (unsigned short*)alloc(16384 * 2);
    unsigned short* WB2 = (unsigned short*)alloc(8192 * 2);
    unsigned* big = (unsigned*)alloc((size_t)N * 128 * 2);   // H fp8 (12.8 MB), later T bf16 (12.8 MB)
    unsigned* packed = (unsigned*)d_out;          // 6.4 MB scratch in d_out (dead after csr_fine2)
    uint2*    epack  = (uint2*)d_in[1];           // {src, w_bits}; overwrites src+dst (dead after fatB scatter)
    unsigned* g1 = (unsigned*)d_in[0];            // G1 bf16 row-major into x's buffer (x dead after gemm1)
    unsigned short* T = (unsigned short*)big;     // T (row-major bf16) overwrites H fp8 (dead after agg1)
    (void)ws_size; (void)n_in; (void)out_size;

    const int PREPB = 97;                     // covers 24768 prep threads
    const int MSB = (E + 4095) / 4096;
    const int GB = (N + 127) / 128;

    hipMemsetAsync(bktcnt, 0, (size_t)NBUK * 4, stream);
    fatA_kernel<<<PREPB + MSB, 256, 0, stream>>>((const unsigned short*)W1, W1, W2, b1, b2,
                                                 WB1, WB2, b1f, b2f, flag, in_sizes[2],
                                                 dst, bktcnt, E, NBUK, PREPB);
    bscan_kernel<<<1, 1024, 0, stream>>>(bktcnt, bofs, bcur, NBUK, E);
    fatB_kernel<<<GB + MSB, 256, 0, stream>>>(x, WB1, (unsigned char*)big, N, flag,
                                              src, dst, bcur, packed, E, NBUK, GB);
    csr_fine2_kernel<<<NBUK, 256, 0, stream>>>(packed, bofs, nmeta, dinv, (unsigned*)epack, N);
    epw_kernel<<<(E + 255) / 256, 256, 0, stream>>>((unsigned*)epack, dinv, E);

    agg128_v9<<<(N + 1) / 2, 128, 0, stream>>>((const uint2*)big, nmeta, epack, b1f, (uint4*)g1, N);
    gemm2b_mfma<<<GB, 256, 0, stream>>>((const unsigned short*)g1, WB2, T, N);
    agg64_final<<<(N + 1) / 2, 128, 0, stream>>>((const uint2*)T, nmeta, epack, b2f, d_out, N, flag);
}

// Round 12
// 280.203 us; speedup vs baseline: 1.7421x; 1.0493x over previous
//
#include <hip/hip_runtime.h>
#include <hip/hip_bf16.h>

typedef __hip_bfloat16 bf16;
typedef short short8 __attribute__((ext_vector_type(8)));
typedef float f32x4 __attribute__((ext_vector_type(4)));
typedef float f32x2 __attribute__((ext_vector_type(2)));

#define NPB 256          // nodes per bucket (coarse radix = dst>>8)
#define MAXBUK 1024      // supports N <= 262144

__device__ __forceinline__ float bf2f_raw(unsigned short u) {
    unsigned x = ((unsigned)u) << 16; float f; __builtin_memcpy(&f, &x, 4); return f;
}
__device__ __forceinline__ unsigned short f2bf_raw(float f) {   // RNE
    unsigned u; __builtin_memcpy(&u, &f, 4);
    u += 0x7FFFu + ((u >> 16) & 1u);
    return (unsigned short)(u >> 16);
}
__device__ __forceinline__ float lo_f(unsigned u) {
    unsigned x = u << 16; float f; __builtin_memcpy(&f, &x, 4); return f;
}
__device__ __forceinline__ float hi_f(unsigned u) {
    unsigned x = u & 0xffff0000u; float f; __builtin_memcpy(&f, &x, 4); return f;
}

// ---------------- fatA: prep role (sniff + weight repack + bias conv) || ms_count role ----------

__global__ __launch_bounds__(256) void fatA_kernel(const unsigned short* __restrict__ W1s,
                                                   const void* __restrict__ W1p,
                                                   const void* __restrict__ W2p,
                                                   const void* __restrict__ b1p,
                                                   const void* __restrict__ b2p,
                                                   unsigned short* __restrict__ WB1,
                                                   unsigned short* __restrict__ WB2,
                                                   float* __restrict__ b1f,
                                                   float* __restrict__ b2f,
                                                   int* __restrict__ flag, int nshorts,
                                                   const int* __restrict__ dst,
                                                   int* __restrict__ bktcnt,
                                                   int E, int nbuk, int prepb) {
    __shared__ int smem[MAXBUK];
    const int tt = threadIdx.x;
    if ((int)blockIdx.x < prepb) {
        const int sample = min(nshorts, 2048);
        int c = 0;
        for (int i = tt; i < sample; i += 256) {
            unsigned e = (W1s[i] >> 7) & 0xFFu;
            if (e >= 140u || (e >= 1u && e <= 40u)) c++;
        }
        smem[tt] = c;
        __syncthreads();
        for (int o = 128; o > 0; o >>= 1) {
            if (tt < o) smem[tt] += smem[tt + o];
            __syncthreads();
        }
        const int isf32 = (smem[0] > sample / 8) ? 1 : 0;
        if (blockIdx.x == 0 && tt == 0) *flag = isf32;

        const int t = blockIdx.x * 256 + tt;
        const int T1 = 16384, T2 = 8192;
        if (t < T1) {
            int j = t & 7, l = (t >> 3) & 63, f = t >> 9;
            int n = f >> 2, kk = f & 3;
            int k = kk * 32 + (l >> 4) * 8 + j;
            int col = n * 16 + (l & 15);
            WB1[t] = isf32 ? f2bf_raw(((const float*)W1p)[k * 128 + col])
                           : ((const unsigned short*)W1p)[k * 128 + col];
        } else if (t < T1 + T2) {
            int o = t - T1;
            int j = o & 7, l = (o >> 3) & 63, f = o >> 9;
            int n = f >> 2, kk = f & 3;
            int k = kk * 32 + (l >> 4) * 8 + j;
            int col = n * 16 + (l & 15);
            WB2[o] = isf32 ? f2bf_raw(((const float*)W2p)[k * 64 + col])
                           : ((const unsigned short*)W2p)[k * 64 + col];
        } else if (t < T1 + T2 + 128) {
            int o = t - T1 - T2;
            b1f[o] = isf32 ? ((const float*)b1p)[o] : bf2f_raw(((const unsigned short*)b1p)[o]);
        } else if (t < T1 + T2 + 192) {
            int o = t - T1 - T2 - 128;
            b2f[o] = isf32 ? ((const float*)b2p)[o] : bf2f_raw(((const unsigned short*)b2p)[o]);
        }
    } else {
        const int e0 = ((int)blockIdx.x - prepb) * 4096;
        const int e1 = min(E, e0 + 4096);
        for (int b = tt; b < nbuk; b += 256) smem[b] = 0;
        __syncthreads();
        for (int e = e0 + tt; e < e1; e += 256) atomicAdd(&smem[dst[e] >> 8], 1);
        __syncthreads();
        for (int b = tt; b < nbuk; b += 256) {
            int c = smem[b];
            if (c) atomicAdd(&bktcnt[b], c);
        }
    }
}

// 2) bscan: exclusive scan of bucket totals -> bofs/bcur.
__global__ __launch_bounds__(1024) void bscan_kernel(const int* __restrict__ bktcnt,
                                                     int* __restrict__ bofs,
                                                     int* __restrict__ bcur,
                                                     int nbuk, int total) {
    __shared__ int ps[1024];
    const int t = threadIdx.x;
    int v = (t < nbuk) ? bktcnt[t] : 0;
    ps[t] = v;
    __syncthreads();
    for (int o = 1; o < 1024; o <<= 1) {
        int u = (t >= o) ? ps[t - o] : 0;
        __syncthreads();
        ps[t] += u;
        __syncthreads();
    }
    if (t < nbuk) {
        int ex = ps[t] - v;
        bofs[t] = ex;
        bcur[t] = ex;
    }
    if (t == 0) bofs[nbuk] = total;
}

// 3) ms_scatter (standalone again; fatB fusion measured +5us): packed = (dst&255)<<24 | src.
__global__ __launch_bounds__(256) void ms_scatter_kernel(const int* __restrict__ src,
                                                         const int* __restrict__ dst,
                                                         int* __restrict__ bcur,
                                                         unsigned* __restrict__ packed,
                                                         int E, int nbuk) {
    __shared__ int cnt[MAXBUK];
    __shared__ int gbase[MAXBUK];
    const int t = threadIdx.x;
    const int e0 = blockIdx.x * 4096;
    const int e1 = min(E, e0 + 4096);
    for (int b = t; b < nbuk; b += 256) cnt[b] = 0;
    __syncthreads();
    for (int e = e0 + t; e < e1; e += 256) atomicAdd(&cnt[dst[e] >> 8], 1);
    __syncthreads();
    for (int b = t; b < nbuk; b += 256) {
        int c = cnt[b];
        gbase[b] = c ? atomicAdd(&bcur[b], c) : 0;
        cnt[b] = 0;
    }
    __syncthreads();
    for (int e = e0 + t; e < e1; e += 256) {
        int d = dst[e];
        int b = d >> 8;
        int r = atomicAdd(&cnt[b], 1);
        packed[gbase[b] + r] = ((unsigned)(d & 255) << 24) | (unsigned)src[e];
    }
}

// 4) csr_fine2: per-node nmeta {base,deg} + dinv; place edge src ids into csrc (4B/edge).
__global__ __launch_bounds__(256) void csr_fine2_kernel(const unsigned* __restrict__ packed,
                                                        const int* __restrict__ bofs,
                                                        uint2* __restrict__ nmeta,
                                                        float* __restrict__ dinv,
                                                        int* __restrict__ csrc, int n) {
    __shared__ int cnt2[NPB];
    __shared__ int cur[NPB];
    const int t = threadIdx.x;
    const int b = blockIdx.x;
    const int node0 = b << 8;
    const int nn = min(NPB, n - node0);
    cnt2[t] = 0;
    __syncthreads();
    const int beg = bofs[b], end = bofs[b + 1];
    for (int i = beg + t; i < end; i += 256) atomicAdd(&cnt2[packed[i] >> 24], 1);
    __syncthreads();
    int c = cnt2[t];
    cur[t] = c;
    __syncthreads();
    for (int o = 1; o < 256; o <<= 1) {        // inclusive scan over 256 local counts
        int u = (t >= o) ? cur[t - o] : 0;
        __syncthreads();
        cur[t] += u;
        __syncthreads();
    }
    const int base = beg + cur[t] - c;          // exclusive
    if (t < nn) {
        nmeta[node0 + t] = make_uint2((unsigned)base, (unsigned)c);
        dinv[node0 + t] = rsqrtf((float)(c + 1));
    }
    __syncthreads();
    cur[t] = base;
    __syncthreads();
    for (int i = beg + t; i < end; i += 256) {
        unsigned u = packed[i];
        int pos = atomicAdd(&cur[u >> 24], 1);
        csrc[pos] = (int)(u & 0xFFFFFFu);
    }
}

// ---------------- GEMM1' (MFMA): H'[v] = dinv[v] * (X * W1)[v], FP8-E4M3 out ----------------
// dinv-factoring: per-edge weights vanish from aggregation entirely (out = di*(sum H'[j] + H'[i]) + b).
// Runs AFTER csr_fine2 (needs dinv). Xs/Cs LDS unioned (34816 B).

__global__ __launch_bounds__(256) void gemm1p_mfma(const void* __restrict__ Xp,
                                                   const unsigned short* __restrict__ WB1,
                                                   const float* __restrict__ dinv,
                                                   unsigned char* __restrict__ Hf8, int nrows,
                                                   const int* __restrict__ flag) {
    __shared__ __align__(16) char smem[34816];
    unsigned short* Xs = (unsigned short*)smem;   // [128][136]
    unsigned short* Cs = (unsigned short*)smem;   // [128][68] (overlays Xs after barrier)
    const int t = threadIdx.x;
    const int r0 = blockIdx.x * 128;
    const int isf32 = *flag;

    if (isf32) {
        const float4* Xg = (const float4*)Xp;
        #pragma unroll
        for (int i = 0; i < 16; ++i) {
            int idx = t + 256 * i;
            int row = idx >> 5, c4 = idx & 31;
            float4 v = {0.f, 0.f, 0.f, 0.f};
            if (r0 + row < nrows) v = Xg[(size_t)(r0 + row) * 32 + c4];
            unsigned lo = (unsigned)f2bf_raw(v.x) | ((unsigned)f2bf_raw(v.y) << 16);
            unsigned hi = (unsigned)f2bf_raw(v.z) | ((unsigned)f2bf_raw(v.w) << 16);
            *reinterpret_cast<uint2*>(&Xs[row * 136 + c4 * 4]) = make_uint2(lo, hi);
        }
    } else {
        const uint4* Xg = (const uint4*)Xp;
        #pragma unroll
        for (int i = 0; i < 8; ++i) {
            int idx = t + 256 * i;
            int row = idx >> 4, c8 = idx & 15;
            uint4 v = {0u, 0u, 0u, 0u};
            if (r0 + row < nrows) v = Xg[(size_t)(r0 + row) * 16 + c8];
            *reinterpret_cast<uint4*>(&Xs[row * 136 + c8 * 8]) = v;
        }
    }
    __syncthreads();

    const int lane = t & 63, w = t >> 6;
    const int m0 = w * 32;
    short8 a[2][4];
    #pragma unroll
    for (int rt = 0; rt < 2; ++rt)
        #pragma unroll
        for (int kk = 0; kk < 4; ++kk)
            a[rt][kk] = *reinterpret_cast<const short8*>(
                &Xs[(m0 + rt * 16 + (lane & 15)) * 136 + kk * 32 + (lane >> 4) * 8]);
    __syncthreads();              // Xs dead; Cs overlays

    for (int p = 0; p < 2; ++p) {
        short8 b[4][4];
        #pragma unroll
        for (int n = 0; n < 4; ++n)
            #pragma unroll
            for (int kk = 0; kk < 4; ++kk)
                b[n][kk] = *reinterpret_cast<const short8*>(
                    WB1 + (size_t)(((p * 4 + n) * 4 + kk) * 64 + lane) * 8);
        f32x4 acc[2][4];
        #pragma unroll
        for (int rt = 0; rt < 2; ++rt)
            #pragma unroll
            for (int n = 0; n < 4; ++n) {
                acc[rt][n] = (f32x4){0.f, 0.f, 0.f, 0.f};
                #pragma unroll
                for (int kk = 0; kk < 4; ++kk)
                    acc[rt][n] = __builtin_amdgcn_mfma_f32_16x16x32_bf16(
                        a[rt][kk], b[n][kk], acc[rt][n], 0, 0, 0);
            }
        if (p) __syncthreads();
        #pragma unroll
        for (int rt = 0; rt < 2; ++rt)
            #pragma unroll
            for (int n = 0; n < 4; ++n)
                #pragma unroll
                for (int r = 0; r < 4; ++r) {
                    int row = m0 + rt * 16 + (lane >> 4) * 4 + r;
                    Cs[row * 68 + n * 16 + (lane & 15)] = f2bf_raw(acc[rt][n][r]);
                }
        __syncthreads();
        // fp8 epilogue with dinv scaling: 128 rows x 8 chunks(8ch) -> 4 iters
        #pragma unroll
        for (int i = 0; i < 4; ++i) {
            int idx = t + 256 * i;
            int row = idx >> 3, c8 = idx & 7;
            if (r0 + row < nrows) {
                float dv = dinv[r0 + row];
                uint2 va = *reinterpret_cast<const uint2*>(&Cs[row * 68 + c8 * 8]);
                uint2 vb = *reinterpret_cast<const uint2*>(&Cs[row * 68 + c8 * 8 + 4]);
                int w0 = __builtin_amdgcn_cvt_pk_fp8_f32(dv * lo_f(va.x), dv * hi_f(va.x), 0, false);
                w0 = __builtin_amdgcn_cvt_pk_fp8_f32(dv * lo_f(va.y), dv * hi_f(va.y), w0, true);
                int w1 = __builtin_amdgcn_cvt_pk_fp8_f32(dv * lo_f(vb.x), dv * hi_f(vb.x), 0, false);
                w1 = __builtin_amdgcn_cvt_pk_fp8_f32(dv * lo_f(vb.y), dv * hi_f(vb.y), w1, true);
                *reinterpret_cast<uint2*>(Hf8 + (size_t)(r0 + row) * 128 + p * 64 + c8 * 8) =
                    make_uint2((unsigned)w0, (unsigned)w1);
            }
        }
        if (!p) __syncthreads();
    }
}

// ---------------- Aggregation v10 (layer 1): weightless fp8 gather, 4 groups x 16 subs ----------
// out[i] = relu(di * (sum_j H'[j] + H'[i]) + b1) -- no per-edge weights (dinv-factored).

__device__ __forceinline__ void accf8_nw(f32x2* acc, uint2 v) {
    acc[0] += __builtin_amdgcn_cvt_pk_f32_fp8(v.x, false);
    acc[1] += __builtin_amdgcn_cvt_pk_f32_fp8(v.x, true);
    acc[2] += __builtin_amdgcn_cvt_pk_f32_fp8(v.y, false);
    acc[3] += __builtin_amdgcn_cvt_pk_f32_fp8(v.y, true);
}

__global__ __launch_bounds__(128) void agg128_v10(const uint2* __restrict__ H2,
                                                  const uint2* __restrict__ nmeta,
                                                  const int* __restrict__ csrc,
                                                  const float* __restrict__ biasf,
                                                  uint4* __restrict__ G4, int n) {
    const int lane = threadIdx.x & 63;
    const int g = lane >> 4;          // 4 edge groups
    const int sub = lane & 15;        // 8B chunk of the 128B fp8 row (8 channels)
    const int node = blockIdx.x * 2 + (threadIdx.x >> 6);
    if (node >= n) return;

    uint2 vself = H2[((unsigned)node << 4) + (unsigned)sub];

    const uint2 meta = nmeta[node];
    const int base = (int)meta.x;
    const int cnt = (int)meta.y;
    const int end = base + cnt;
    const float di = rsqrtf((float)(cnt + 1));

    f32x2 acc[4];
    #pragma unroll
    for (int i = 0; i < 4; ++i) acc[i] = (f32x2){0.f, 0.f};
    if (g == 0) accf8_nw(acc, vself);           // self term (H' already dinv-scaled)

    int j = base;
    for (; j + 15 < end; j += 16) {             // 16 edges, 4 gathers/lane in flight
        int s0 = csrc[j + g];
        int s1 = csrc[j + 4 + g];
        int s2 = csrc[j + 8 + g];
        int s3 = csrc[j + 12 + g];
        uint2 v0 = H2[((unsigned)s0 << 4) + (unsigned)sub];
        uint2 v1 = H2[((unsigned)s1 << 4) + (unsigned)sub];
        uint2 v2 = H2[((unsigned)s2 << 4) + (unsigned)sub];
        uint2 v3 = H2[((unsigned)s3 << 4) + (unsigned)sub];
        accf8_nw(acc, v0);
        accf8_nw(acc, v1);
        accf8_nw(acc, v2);
        accf8_nw(acc, v3);
    }
    for (; j + 7 < end; j += 8) {               // 8 edges
        int s0 = csrc[j + g];
        int s1 = csrc[j + 4 + g];
        uint2 v0 = H2[((unsigned)s0 << 4) + (unsigned)sub];
        uint2 v1 = H2[((unsigned)s1 << 4) + (unsigned)sub];
        accf8_nw(acc, v0);
        accf8_nw(acc, v1);
    }
    for (; j + 3 < end; j += 4) {               // 4 edges
        int s0 = csrc[j + g];
        uint2 v0 = H2[((unsigned)s0 << 4) + (unsigned)sub];
        accf8_nw(acc, v0);
    }
    if (j + g < end) {                          // tail (<4 edges), group-predicated
        int s0 = csrc[j + g];
        uint2 v0 = H2[((unsigned)s0 << 4) + (unsigned)sub];
        accf8_nw(acc, v0);
    }

    float a8[8];
    #pragma unroll
    for (int i = 0; i < 4; ++i) { a8[2 * i] = acc[i].x; a8[2 * i + 1] = acc[i].y; }
    #pragma unroll
    for (int i = 0; i < 8; ++i) {               // combine the 4 edge-groups (lane bits 4,5)
        a8[i] += __shfl_xor(a8[i], 16, 64);
        a8[i] += __shfl_xor(a8[i], 32, 64);
    }

    if (g == 0) {                               // lanes 0..15: channels [sub*8, sub*8+8)
        const float4* b4 = (const float4*)biasf;
        float4 blo = b4[sub * 2], bhi = b4[sub * 2 + 1];
        a8[0] = fmaxf(fmaf(di, a8[0], blo.x), 0.f);
        a8[1] = fmaxf(fmaf(di, a8[1], blo.y), 0.f);
        a8[2] = fmaxf(fmaf(di, a8[2], blo.z), 0.f);
        a8[3] = fmaxf(fmaf(di, a8[3], blo.w), 0.f);
        a8[4] = fmaxf(fmaf(di, a8[4], bhi.x), 0.f);
        a8[5] = fmaxf(fmaf(di, a8[5], bhi.y), 0.f);
        a8[6] = fmaxf(fmaf(di, a8[6], bhi.z), 0.f);
        a8[7] = fmaxf(fmaf(di, a8[7], bhi.w), 0.f);
        uint4 o;
        o.x = (unsigned)f2bf_raw(a8[0]) | ((unsigned)f2bf_raw(a8[1]) << 16);
        o.y = (unsigned)f2bf_raw(a8[2]) | ((unsigned)f2bf_raw(a8[3]) << 16);
        o.z = (unsigned)f2bf_raw(a8[4]) | ((unsigned)f2bf_raw(a8[5]) << 16);
        o.w = (unsigned)f2bf_raw(a8[6]) | ((unsigned)f2bf_raw(a8[7]) << 16);
        G4[((unsigned)node << 4) + (unsigned)sub] = o;    // G1 bf16 row-major, 16B/lane
    }
}

// ---------------- GEMM2b' (MFMA): T'[v] = dinv[v] * (G1 * W2)[v], bf16 out ----------------

__global__ __launch_bounds__(256) void gemm2bp_mfma(const unsigned short* __restrict__ X,
                                                    const unsigned short* __restrict__ WB2,
                                                    const float* __restrict__ dinv,
                                                    unsigned short* __restrict__ T, int nrows) {
    __shared__ __align__(16) char smem[34816];
    unsigned short* Xs = (unsigned short*)smem;   // [128][136]
    unsigned short* Cs = (unsigned short*)smem;   // [128][68] (overlays Xs after barrier)
    const int t = threadIdx.x;
    const int r0 = blockIdx.x * 128;

    const uint4* Xg = (const uint4*)X;
    #pragma unroll
    for (int i = 0; i < 8; ++i) {
        int idx = t + 256 * i;
        int row = idx >> 4, c8 = idx & 15;
        uint4 v = {0u, 0u, 0u, 0u};
        if (r0 + row < nrows) v = Xg[(size_t)(r0 + row) * 16 + c8];
        *reinterpret_cast<uint4*>(&Xs[row * 136 + c8 * 8]) = v;
    }
    __syncthreads();

    const int lane = t & 63, w = t >> 6;
    const int m0 = w * 32;
    short8 a[2][4];
    #pragma unroll
    for (int rt = 0; rt < 2; ++rt)
        #pragma unroll
        for (int kk = 0; kk < 4; ++kk)
            a[rt][kk] = *reinterpret_cast<const short8*>(
                &Xs[(m0 + rt * 16 + (lane & 15)) * 136 + kk * 32 + (lane >> 4) * 8]);
    __syncthreads();              // Xs dead; Cs overlays

    short8 b[4][4];
    #pragma unroll
    for (int n = 0; n < 4; ++n)
        #pragma unroll
        for (int kk = 0; kk < 4; ++kk)
            b[n][kk] = *reinterpret_cast<const short8*>(
                WB2 + (size_t)((n * 4 + kk) * 64 + lane) * 8);

    f32x4 acc[2][4];
    #pragma unroll
    for (int rt = 0; rt < 2; ++rt)
        #pragma unroll
        for (int n = 0; n < 4; ++n) {
            acc[rt][n] = (f32x4){0.f, 0.f, 0.f, 0.f};
            #pragma unroll
            for (int kk = 0; kk < 4; ++kk)
                acc[rt][n] = __builtin_amdgcn_mfma_f32_16x16x32_bf16(
                    a[rt][kk], b[n][kk], acc[rt][n], 0, 0, 0);
        }

    #pragma unroll
    for (int rt = 0; rt < 2; ++rt)
        #pragma unroll
        for (int n = 0; n < 4; ++n)
            #pragma unroll
            for (int r = 0; r < 4; ++r) {
                int row = m0 + rt * 16 + (lane >> 4) * 4 + r;
                Cs[row * 68 + n * 16 + (lane & 15)] = f2bf_raw(acc[rt][n][r]);
            }
    __syncthreads();
    #pragma unroll
    for (int i = 0; i < 8; ++i) {
        int idx = t + 256 * i;
        int row = idx >> 4, c4 = idx & 15;
        if (r0 + row < nrows) {
            float dv = dinv[r0 + row];
            uint2 v = *reinterpret_cast<const uint2*>(&Cs[row * 68 + c4 * 4]);
            unsigned ox = (unsigned)f2bf_raw(dv * lo_f(v.x)) |
                          ((unsigned)f2bf_raw(dv * hi_f(v.x)) << 16);
            unsigned oy = (unsigned)f2bf_raw(dv * lo_f(v.y)) |
                          ((unsigned)f2bf_raw(dv * hi_f(v.y)) << 16);
            *reinterpret_cast<uint2*>(T + (size_t)(r0 + row) * 64 + c4 * 4) = make_uint2(ox, oy);
        }
    }
}

// ---------------- Aggregation 2 v3: weightless bf16 gather + bias + log_softmax ----------------
// o[i] = di * (sum_j T'[j] + T'[i]) + b2, then log_softmax over the 64 channels.

__device__ __forceinline__ void acc4v_nw(f32x2* acc, uint2 v) {
    acc[0] += (f32x2){lo_f(v.x), hi_f(v.x)};
    acc[1] += (f32x2){lo_f(v.y), hi_f(v.y)};
}

__global__ __launch_bounds__(128) void agg64_v3(const uint2* __restrict__ T2,
                                                const uint2* __restrict__ nmeta,
                                                const int* __restrict__ csrc,
                                                const float* __restrict__ b2f,
                                                void* __restrict__ OUTv, int n,
                                                const int* __restrict__ flag) {
    const int lane = threadIdx.x & 63;
    const int g = lane >> 4;          // 4 edge groups
    const int sub = lane & 15;        // 8B chunk (4 channels) of the 128B bf16 row
    const int node = blockIdx.x * 2 + (threadIdx.x >> 6);
    if (node >= n) return;
    const int outf32 = *flag;

    uint2 vself = T2[((unsigned)node << 4) + (unsigned)sub];

    const uint2 meta = nmeta[node];
    const int base = (int)meta.x;
    const int cnt = (int)meta.y;
    const int end = base + cnt;
    const float di = rsqrtf((float)(cnt + 1));

    f32x2 acc[2];
    acc[0] = (f32x2){0.f, 0.f};
    acc[1] = (f32x2){0.f, 0.f};
    if (g == 0) acc4v_nw(acc, vself);           // self term (T' already dinv-scaled)

    int j = base;
    for (; j + 15 < end; j += 16) {             // 16 edges, 4 gathers/lane in flight
        int s0 = csrc[j + g];
        int s1 = csrc[j + 4 + g];
        int s2 = csrc[j + 8 + g];
        int s3 = csrc[j + 12 + g];
        uint2 v0 = T2[((unsigned)s0 << 4) + (unsigned)sub];
        uint2 v1 = T2[((unsigned)s1 << 4) + (unsigned)sub];
        uint2 v2 = T2[((unsigned)s2 << 4) + (unsigned)sub];
        uint2 v3 = T2[((unsigned)s3 << 4) + (unsigned)sub];
        acc4v_nw(acc, v0);
        acc4v_nw(acc, v1);
        acc4v_nw(acc, v2);
        acc4v_nw(acc, v3);
    }
    for (; j + 7 < end; j += 8) {               // 8 edges
        int s0 = csrc[j + g];
        int s1 = csrc[j + 4 + g];
        uint2 v0 = T2[((unsigned)s0 << 4) + (unsigned)sub];
        uint2 v1 = T2[((unsigned)s1 << 4) + (unsigned)sub];
        acc4v_nw(acc, v0);
        acc4v_nw(acc, v1);
    }
    for (; j + 3 < end; j += 4) {               // 4 edges
        int s0 = csrc[j + g];
        uint2 v0 = T2[((unsigned)s0 << 4) + (unsigned)sub];
        acc4v_nw(acc, v0);
    }
    if (j + g < end) {                          // tail (<4 edges), group-predicated
        int s0 = csrc[j + g];
        uint2 v0 = T2[((unsigned)s0 << 4) + (unsigned)sub];
        acc4v_nw(acc, v0);
    }

    float a4[4] = {acc[0].x, acc[0].y, acc[1].x, acc[1].y};
    #pragma unroll
    for (int i = 0; i < 4; ++i) {               // combine the 4 edge-groups (lane bits 4,5)
        a4[i] += __shfl_xor(a4[i], 16, 64);
        a4[i] += __shfl_xor(a4[i], 32, 64);
    }

    if (g == 0) {                               // lanes 0..15: channels [sub*4, sub*4+4)
        float4 bb = ((const float4*)b2f)[sub];
        a4[0] = fmaf(di, a4[0], bb.x);
        a4[1] = fmaf(di, a4[1], bb.y);
        a4[2] = fmaf(di, a4[2], bb.z);
        a4[3] = fmaf(di, a4[3], bb.w);

        float m = fmaxf(fmaxf(a4[0], a4[1]), fmaxf(a4[2], a4[3]));
        m = fmaxf(m, __shfl_xor(m, 1, 64));
        m = fmaxf(m, __shfl_xor(m, 2, 64));
        m = fmaxf(m, __shfl_xor(m, 4, 64));
        m = fmaxf(m, __shfl_xor(m, 8, 64));
        float s = __expf(a4[0] - m) + __expf(a4[1] - m) +
                  __expf(a4[2] - m) + __expf(a4[3] - m);
        s += __shfl_xor(s, 1, 64);
        s += __shfl_xor(s, 2, 64);
        s += __shfl_xor(s, 4, 64);
        s += __shfl_xor(s, 8, 64);
        const float lse = m + __logf(s);

        if (outf32) {
            float4 o = {a4[0] - lse, a4[1] - lse, a4[2] - lse, a4[3] - lse};
            ((float4*)OUTv)[(size_t)node * 16 + sub] = o;
        } else {
            uint2 o;
            o.x = (unsigned)f2bf_raw(a4[0] - lse) | ((unsigned)f2bf_raw(a4[1] - lse) << 16);
            o.y = (unsigned)f2bf_raw(a4[2] - lse) | ((unsigned)f2bf_raw(a4[3] - lse) << 16);
            ((uint2*)OUTv)[(size_t)node * 16 + sub] = o;
        }
    }
}

// ---------------- launch ----------------

extern "C" void kernel_launch(void* const* d_in, const int* in_sizes, int n_in,
                              void* d_out, int out_size, void* d_ws, size_t ws_size,
                              hipStream_t stream) {
    const void* x  = d_in[0];
    const int*  ei = (const int*)d_in[1];
    const void* W1 = d_in[2];
    const void* b1 = d_in[3];
    const void* W2 = d_in[4];
    const void* b2 = d_in[5];

    const int N = in_sizes[0] / 128;
    const int E = in_sizes[1] / 2;
    const int* src = ei;
    const int* dst = ei + E;
    const int NBUK = (N + NPB - 1) / NPB;     // 391 for N=100K

    char* p = (char*)d_ws;
    auto alloc = [&](size_t bytes) { char* q = p; p += (bytes + 255) & ~255ull; return q; };
    int*   flag   = (int*)  alloc(4);
    uint2* nmeta  = (uint2*)alloc((size_t)N * 8);
    float* dinv   = (float*)alloc((size_t)N * 4);
    int*   bktcnt = (int*)  alloc((size_t)NBUK * 4);
    int*   bofs   = (int*)  alloc((size_t)(NBUK + 1) * 4);
    int*   bcur   = (int*)  alloc((size_t)NBUK * 4);
    float* b1f    = (float*)alloc(128 * 4);
    float* b2f    = (float*)alloc(64 * 4);
    unsigned short* WB1 = (unsigned short*)alloc(16384 * 2);
    unsigned short* WB2 = (unsigned short*)alloc(8192 * 2);
    unsigned* big = (unsigned*)alloc((size_t)N * 128 * 2);   // H' fp8 (12.8 MB), later T' bf16 (12.8 MB)
    unsigned* packed = (unsigned*)d_out;          // 6.4 MB scratch in d_out (dead after csr_fine2)
    int*      csrc   = (int*)d_in[1];             // 4B/edge; overwrites src (dead after ms_scatter)
    unsigned* g1 = (unsigned*)d_in[0];            // G1 bf16 row-major into x's buffer (x dead after gemm1)
    unsigned short* T = (unsigned short*)big;     // T' bf16 overwrites H' fp8 (dead after agg1)
    (void)ws_size; (void)n_in; (void)out_size;

    const int PREPB = 97;                     // covers 24768 prep threads
    const int MSB = (E + 4095) / 4096;
    const int GB = (N + 127) / 128;

    hipMemsetAsync(bktcnt, 0, (size_t)NBUK * 4, stream);
    fatA_kernel<<<PREPB + MSB, 256, 0, stream>>>((const unsigned short*)W1, W1, W2, b1, b2,
                                                 WB1, WB2, b1f, b2f, flag, in_sizes[2],
                                                 dst, bktcnt, E, NBUK, PREPB);
    bscan_kernel<<<1, 1024, 0, stream>>>(bktcnt, bofs, bcur, NBUK, E);
    ms_scatter_kernel<<<MSB, 256, 0, stream>>>(src, dst, bcur, packed, E, NBUK);
    csr_fine2_kernel<<<NBUK, 256, 0, stream>>>(packed, bofs, nmeta, dinv, csrc, N);

    gemm1p_mfma<<<GB, 256, 0, stream>>>(x, WB1, dinv, (unsigned char*)big, N, flag);
    agg128_v10<<<(N + 1) / 2, 128, 0, stream>>>((const uint2*)big, nmeta, csrc, b1f, (uint4*)g1, N);
    gemm2bp_mfma<<<GB, 256, 0, stream>>>((const unsigned short*)g1, WB2, dinv, T, N);
    agg64_v3<<<(N + 1) / 2, 128, 0, stream>>>((const uint2*)T, nmeta, csrc, b2f, d_out, N, flag);
}